// Round 8
// baseline (381.871 us; speedup 1.0000x reference)
//
#include <hip/hip_runtime.h>

typedef unsigned short u16;
typedef unsigned int u32;
typedef float f32x4 __attribute__((ext_vector_type(4)));
typedef short bf16x8 __attribute__((ext_vector_type(8)));
typedef unsigned short u16x8 __attribute__((ext_vector_type(8)));

#define SL 33554432u   // one 67MB slot, in u16 elements

__device__ __forceinline__ float bf2f(u16 u) {
  u32 v = ((u32)u) << 16;
  return __builtin_bit_cast(float, v);
}
__device__ __forceinline__ u16 f2bf(float f) {
  u32 i = __builtin_bit_cast(u32, f);
  i += 0x7fffu + ((i >> 16) & 1u);
  return (u16)(i >> 16);
}

#define GLDS16(g, l) __builtin_amdgcn_global_load_lds( \
    (const __attribute__((address_space(1))) void*)(g), \
    (__attribute__((address_space(3))) void*)(l), 16, 0, 0)

// ---- shared GEMM core: 128x128 tile, BK=64, 4 waves (2x2), bf16 MFMA ------
// A,B row-major with contiguous K (B^T form): C[m][n] = sum_k A[m][k]*B[n][k]
// LDS: linear dest (global_load_lds), global src pre-swizzled slot^(row&7).
// SWAP=false: col(lane&15)=B-row, reg-quad=4 consecutive A-rows.
// SWAP=true : col(lane&15)=A-row, reg-quad=4 consecutive B-rows.
__device__ __forceinline__ void stage128(const u16* gbase, int ldk, u16* lds, int tid) {
  #pragma unroll
  for (int rep = 0; rep < 4; ++rep) {
    int c = tid + rep * 256;            // chunk 0..1023
    int row = c >> 3, slot = c & 7;
    const u16* g = gbase + (size_t)row * ldk + ((slot ^ (row & 7)) << 3);
    GLDS16(g, lds + c * 8);
  }
}

template <bool SWAP>
__device__ __forceinline__ void mfma128(const u16* As, const u16* Bs, int lane,
                                        int wm0, int wn0, f32x4 acc[4][4]) {
  #pragma unroll
  for (int kk = 0; kk < 2; ++kk) {
    bf16x8 a[4], b[4];
    #pragma unroll
    for (int mi = 0; mi < 4; ++mi) {
      int r = wm0 + mi * 16 + (lane & 15);
      int c16 = (kk * 4 + (lane >> 4)) ^ (r & 7);
      a[mi] = *(const bf16x8*)(As + r * 64 + c16 * 8);
    }
    #pragma unroll
    for (int ni = 0; ni < 4; ++ni) {
      int r = wn0 + ni * 16 + (lane & 15);
      int c16 = (kk * 4 + (lane >> 4)) ^ (r & 7);
      b[ni] = *(const bf16x8*)(Bs + r * 64 + c16 * 8);
    }
    #pragma unroll
    for (int mi = 0; mi < 4; ++mi)
      #pragma unroll
      for (int ni = 0; ni < 4; ++ni)
        acc[mi][ni] = SWAP
          ? __builtin_amdgcn_mfma_f32_16x16x32_bf16(b[ni], a[mi], acc[mi][ni], 0, 0, 0)
          : __builtin_amdgcn_mfma_f32_16x16x32_bf16(a[mi], b[ni], acc[mi][ni], 0, 0, 0);
  }
}

template <bool SWAP>
__device__ __forceinline__ void gemm_core(const u16* A, int ldkA, const u16* B, int ldkB,
                                          int NT, u16* As, u16* Bs,
                                          int tid, int lane, int wm0, int wn0,
                                          f32x4 acc[4][4]) {
  for (int t = 0; t < NT; ++t) {
    stage128(A + t * 64, ldkA, As, tid);
    stage128(B + t * 64, ldkB, Bs, tid);
    __syncthreads();
    mfma128<SWAP>(As, Bs, lane, wm0, wn0, acc);
    __syncthreads();
  }
}

// ---------------- weight cast ----------------------------------------------
__global__ __launch_bounds__(256) void k_castw(
    const float* __restrict__ Wq, const float* __restrict__ Wk,
    const float* __restrict__ Wv, const float* __restrict__ Wo,
    u16* __restrict__ Wb) {
  int idx = blockIdx.x * 256 + threadIdx.x;     // 32768 chunks of 8
  int w = idx >> 13, off = idx & 8191;
  const float* src = (w == 0) ? Wq : (w == 1) ? Wk : (w == 2) ? Wv : Wo;
  const float4* s = (const float4*)(src + (size_t)off * 8);
  float4 a = s[0], b = s[1];
  u16x8 o;
  o[0] = f2bf(a.x); o[1] = f2bf(a.y); o[2] = f2bf(a.z); o[3] = f2bf(a.w);
  o[4] = f2bf(b.x); o[5] = f2bf(b.y); o[6] = f2bf(b.z); o[7] = f2bf(b.w);
  *(u16x8*)(Wb + (size_t)w * 65536 + (size_t)off * 8) = o;
}

// ---------------- K1: fused cast + q/k/v projection GEMM -------------------
// grid 2048 = 1024 m-tiles x 2 n-halves, XCD-swizzled (both halves of an
// m-tile co-resident on one XCD). A-panel (128x256, x f32 -> bf16) staged to
// LDS ONCE, reused across w={q,k,v} x 4 K-tiles; only B (16 KB) staged per
// phase via global_load_lds. LDS 80 KB -> 2 blocks/CU.
__global__ __launch_bounds__(256) void k_proj_mm(
    const float* __restrict__ x, const u16* __restrict__ Wb,
    const float* __restrict__ bq, const float* __restrict__ bk, const float* __restrict__ bv,
    u16* __restrict__ qt, u16* __restrict__ kt, u16* __restrict__ vt, float scaling) {
  __shared__ __align__(16) u16 As[4 * 8192];    // 64 KB: 4 K-tile planes
  __shared__ __align__(16) u16 Bs[8192];        // 16 KB
  const int tid = threadIdx.x, lane = tid & 63, wave = tid >> 6;
  const int wm0 = (wave >> 1) * 64, wn0 = (wave & 1) * 64;
  const int bid = blockIdx.x;
  const int sb = (bid & 7) * 256 + (bid >> 3);   // bijective: 2048 % 8 == 0
  const int mt = sb >> 1, n0 = (sb & 1) * 128;
  const int m0 = mt * 128;

  // ---- stage A panel once: f32 load, bf16 convert, swizzled ds_write ----
  {
    const float* xp = x + (size_t)m0 * 256;
    #pragma unroll
    for (int it = 0; it < 16; ++it) {
      int g = tid + it * 256;             // 4096 chunks of 8 elements
      int row = g >> 5, col8 = g & 31;
      int ktp = col8 >> 3, slot = col8 & 7;
      const float* src = xp + row * 256 + col8 * 8;
      float4 a = *(const float4*)src, b = *(const float4*)(src + 4);
      u16x8 o;
      o[0]=f2bf(a.x); o[1]=f2bf(a.y); o[2]=f2bf(a.z); o[3]=f2bf(a.w);
      o[4]=f2bf(b.x); o[5]=f2bf(b.y); o[6]=f2bf(b.z); o[7]=f2bf(b.w);
      *(u16x8*)(As + ktp * 8192 + row * 64 + ((slot ^ (row & 7)) << 3)) = o;
    }
  }

  #pragma unroll 1
  for (int w = 0; w < 3; ++w) {
    f32x4 acc[4][4];
    #pragma unroll
    for (int mi = 0; mi < 4; ++mi)
      #pragma unroll
      for (int ni = 0; ni < 4; ++ni) acc[mi][ni] = (f32x4){0.f, 0.f, 0.f, 0.f};

    const u16* Bw = Wb + w * 65536 + (size_t)n0 * 256;
    for (int ktt = 0; ktt < 4; ++ktt) {
      stage128(Bw + ktt * 64, 256, Bs, tid);
      __syncthreads();                 // drains A ds_writes (first pass) + B glds
      mfma128<true>(As + ktt * 8192, Bs, lane, wm0, wn0, acc);
      __syncthreads();
    }

    const float* bias = (w == 0) ? bq : (w == 1) ? bk : bv;
    u16* dst = (w == 0) ? qt : (w == 1) ? kt : vt;
    const float sc = (w == 0) ? scaling : 1.0f;

    #pragma unroll
    for (int ni = 0; ni < 4; ++ni) {
      int f = n0 + wn0 + ni * 16 + (lane >> 4) * 4;   // quad base, %4==0
      int h = f >> 5, d = f & 31;
      float4 bb = *(const float4*)(bias + f);
      #pragma unroll
      for (int mi = 0; mi < 4; ++mi) {
        int m = m0 + wm0 + mi * 16 + (lane & 15);
        int n = m & 3, i = (m >> 2) & 511, r = m >> 11;
        size_t o = ((size_t)((n * 8 + h) * 512 + i)) * 2048 + r * 32 + d;
        ushort4 wv4;
        wv4.x = f2bf((acc[mi][ni][0] + bb.x) * sc);
        wv4.y = f2bf((acc[mi][ni][1] + bb.y) * sc);
        wv4.z = f2bf((acc[mi][ni][2] + bb.z) * sc);
        wv4.w = f2bf((acc[mi][ni][3] + bb.w) * sc);
        *(ushort4*)(dst + o) = wv4;
      }
    }
  }
}

// ---------------- K2a: attention logits GEMM -------------------------------
// grid 512 = 32 nh x 16 tiles, XCD-swizzled. SWAPPED: reg-quad = 4 consecutive j.
__global__ __launch_bounds__(256) void k_attn_mm(
    const u16* __restrict__ qt, const u16* __restrict__ kt, u16* __restrict__ lgt) {
  __shared__ __align__(16) u16 As[128 * 64];
  __shared__ __align__(16) u16 Bs[128 * 64];
  const int tid = threadIdx.x, lane = tid & 63, wave = tid >> 6;
  const int wm0 = (wave >> 1) * 64, wn0 = (wave & 1) * 64;
  const int bid = blockIdx.x;
  const int sb = (bid & 7) * 64 + (bid >> 3);    // 512 % 8 == 0
  const int nh = sb >> 4, tt = sb & 15;
  const int m0 = (tt >> 2) * 128, n0 = (tt & 3) * 128;

  f32x4 acc[4][4];
  #pragma unroll
  for (int mi = 0; mi < 4; ++mi)
    #pragma unroll
    for (int ni = 0; ni < 4; ++ni) acc[mi][ni] = (f32x4){0.f, 0.f, 0.f, 0.f};

  const size_t base = (size_t)nh * 512 * 2048;
  gemm_core<true>(qt + base + (size_t)m0 * 2048, 2048, kt + base + (size_t)n0 * 2048, 2048,
                  32, As, Bs, tid, lane, wm0, wn0, acc);

  #pragma unroll
  for (int mi = 0; mi < 4; ++mi) {
    int row = m0 + wm0 + mi * 16 + (lane & 15);
    #pragma unroll
    for (int ni = 0; ni < 4; ++ni) {
      int col = n0 + wn0 + ni * 16 + (lane >> 4) * 4;
      ushort4 wv4;
      wv4.x = f2bf(acc[mi][ni][0]);
      wv4.y = f2bf(acc[mi][ni][1]);
      wv4.z = f2bf(acc[mi][ni][2]);
      wv4.w = f2bf(acc[mi][ni][3]);
      *(ushort4*)(lgt + (size_t)nh * 262144 + (size_t)row * 512 + col) = wv4;
    }
  }
}

// ---------------- K2b: bias + softmax (barrier-free, per-wave rows) --------
__global__ __launch_bounds__(256) void k_softmax(
    const u16* __restrict__ lgt, const int* __restrict__ dist, const float* __restrict__ rel,
    float* __restrict__ probs, u16* __restrict__ pbf) {
  const int t = threadIdx.x;
  const int lane = t & 63, wv = t >> 6;
  const int b = blockIdx.x;
  const int i = b & 511, n = b >> 9;

  const int* dr = dist + ((size_t)n * 512 + i) * 512 + lane * 8;
  int4 dA = *(const int4*)dr, dB = *(const int4*)(dr + 4);
  int dd[8] = {dA.x, dA.y, dA.z, dA.w, dB.x, dB.y, dB.z, dB.w};
  int u[8];
  #pragma unroll
  for (int j = 0; j < 8; ++j) {
    int v = dd[j] < 0 ? -dd[j] : dd[j];
    int q = (62 * v + 49999) / 50000; if (q > 63) q = 63;
    u[j] = q;
  }

  #pragma unroll
  for (int hh = 0; hh < 2; ++hh) {
    const int h = wv * 2 + hh;
    const int nh = n * 8 + h;
    const u16* lr = lgt + ((size_t)nh * 512 + i) * 512 + lane * 8;
    u16x8 L = *(const u16x8*)lr;
    float vj[8];
    float mx = -1e30f;
    #pragma unroll
    for (int j = 0; j < 8; ++j) {
      vj[j] = bf2f(L[j]) + rel[u[j] * 8 + h];
      mx = fmaxf(mx, vj[j]);
    }
    #pragma unroll
    for (int off = 32; off; off >>= 1) mx = fmaxf(mx, __shfl_xor(mx, off));
    float s = 0.f;
    #pragma unroll
    for (int j = 0; j < 8; ++j) { vj[j] = __expf(vj[j] - mx); s += vj[j]; }
    #pragma unroll
    for (int off = 32; off; off >>= 1) s += __shfl_xor(s, off);
    float inv = 1.0f / s;
    float4 pa, pb;
    pa.x = vj[0]*inv; pa.y = vj[1]*inv; pa.z = vj[2]*inv; pa.w = vj[3]*inv;
    pb.x = vj[4]*inv; pb.y = vj[5]*inv; pb.z = vj[6]*inv; pb.w = vj[7]*inv;
    size_t po = ((size_t)(h * 4 + n) * 512 + i) * 512 + lane * 8;
    *(float4*)(probs + po) = pa;
    *(float4*)(probs + po + 4) = pb;
    u16x8 pc;
    pc[0]=f2bf(pa.x); pc[1]=f2bf(pa.y); pc[2]=f2bf(pa.z); pc[3]=f2bf(pa.w);
    pc[4]=f2bf(pb.x); pc[5]=f2bf(pb.y); pc[6]=f2bf(pb.z); pc[7]=f2bf(pb.w);
    size_t pq = ((size_t)nh * 512 + i) * 512 + lane * 8;
    *(u16x8*)(pbf + pq) = pc;
  }
}

// ---------------- V transpose: vt [nh][i][c] -> vtt [nh][c][i] -------------
__global__ __launch_bounds__(256) void k_vtrans(const u16* __restrict__ vt, u16* __restrict__ vtt) {
  __shared__ u16 ts[64][72];
  const int b = blockIdx.x;             // nh*256 + it*32 + ct
  const int ct_ = b & 31, it = (b >> 5) & 7, nh = b >> 8;
  const int i0 = it * 64, c0 = ct_ * 64;
  const int t = threadIdx.x;
  #pragma unroll
  for (int rep = 0; rep < 2; ++rep) {
    int c = t + rep * 256;
    int r = c >> 3, q = c & 7;
    u16x8 v = *(const u16x8*)(vt + ((size_t)nh * 512 + i0 + r) * 2048 + c0 + q * 8);
    #pragma unroll
    for (int j = 0; j < 8; ++j) ts[r][q * 8 + j] = v[j];
  }
  __syncthreads();
  #pragma unroll
  for (int rep = 0; rep < 2; ++rep) {
    int c = t + rep * 256;
    int rr = c >> 3, q = c & 7;
    u16x8 o;
    #pragma unroll
    for (int j = 0; j < 8; ++j) o[j] = ts[q * 8 + j][rr];
    *(u16x8*)(vtt + ((size_t)nh * 2048 + c0 + rr) * 512 + i0 + q * 8) = o;
  }
}

// ---------------- K3: context GEMM (LDS-transpose epilogue, pad 130) -------
// grid 2048 = 32 nh x 64 tiles, XCD-swizzled. C tile = [c 128][i 128];
// epilogue transposes via LDS and writes 64B d-runs into ct x-layout.
__global__ __launch_bounds__(256) void k_ctx_mm(
    const u16* __restrict__ vtt, const u16* __restrict__ pbf, u16* __restrict__ ct) {
  __shared__ __align__(16) u16 lds[16640];      // staging 16384 U ts 128*130
  u16* As = lds;
  u16* Bs = lds + 8192;
  u16* ts = lds;
  const int tid = threadIdx.x, lane = tid & 63, wave = tid >> 6;
  const int wm0 = (wave >> 1) * 64, wn0 = (wave & 1) * 64;
  const int bid = blockIdx.x;
  const int sb = (bid & 7) * 256 + (bid >> 3);   // 2048 % 8 == 0
  const int nh = sb >> 6, tt = sb & 63;
  const int m0 = (tt >> 2) * 128, n0 = (tt & 3) * 128;
  const int n = nh >> 3, h = nh & 7;

  f32x4 acc[4][4];
  #pragma unroll
  for (int mi = 0; mi < 4; ++mi)
    #pragma unroll
    for (int ni = 0; ni < 4; ++ni) acc[mi][ni] = (f32x4){0.f, 0.f, 0.f, 0.f};

  gemm_core<false>(vtt + (size_t)nh * 1048576 + (size_t)m0 * 512, 512,
                   pbf + (size_t)nh * 262144 + (size_t)n0 * 512, 512,
                   8, As, Bs, tid, lane, wm0, wn0, acc);

  // ts[i_local][c_local], pad 130
  #pragma unroll
  for (int mi = 0; mi < 4; ++mi)
    #pragma unroll
    for (int ni = 0; ni < 4; ++ni) {
      int i_l = wn0 + ni * 16 + (lane & 15);
      #pragma unroll
      for (int q = 0; q < 4; ++q) {
        int c_l = wm0 + mi * 16 + (lane >> 4) * 4 + q;
        ts[i_l * 130 + c_l] = f2bf(acc[mi][ni][q]);
      }
    }
  __syncthreads();
  #pragma unroll
  for (int cc = 0; cc < 2; ++cc) {
    int ch = tid + cc * 256;
    int i_l = ch & 127, r_l = ch >> 7;
    const u16* src = ts + i_l * 130 + r_l * 32;
    int rr = (m0 >> 5) + r_l;
    size_t o = ((size_t)((rr * 512 + n0 + i_l) * 4 + n)) * 256 + h * 32;
    #pragma unroll
    for (int j = 0; j < 4; ++j)
      *(u16x8*)(ct + o + j * 8) = *(const u16x8*)(src + j * 8);
  }
}

// ---------------- K4: output projection GEMM -------------------------------
// SWAPPED: reg-quad = 4 consecutive cols -> float4 stores.
__global__ __launch_bounds__(256) void k_oproj_mm(
    const u16* __restrict__ ct, const u16* __restrict__ Wob,
    const float* __restrict__ bo, float* __restrict__ out) {
  __shared__ __align__(16) u16 As[128 * 64];
  __shared__ __align__(16) u16 Bs[128 * 64];
  const int tid = threadIdx.x, lane = tid & 63, wave = tid >> 6;
  const int wm0 = (wave >> 1) * 64, wn0 = (wave & 1) * 64;
  const int bid = blockIdx.x;
  const int sb = (bid & 7) * 256 + (bid >> 3);
  const int m0 = (sb >> 1) * 128, n0 = (sb & 1) * 128;

  f32x4 acc[4][4];
  #pragma unroll
  for (int mi = 0; mi < 4; ++mi)
    #pragma unroll
    for (int ni = 0; ni < 4; ++ni) acc[mi][ni] = (f32x4){0.f, 0.f, 0.f, 0.f};

  gemm_core<true>(ct + (size_t)m0 * 256, 256, Wob + (size_t)n0 * 256, 256,
                  4, As, Bs, tid, lane, wm0, wn0, acc);

  #pragma unroll
  for (int ni = 0; ni < 4; ++ni) {
    int col = n0 + wn0 + ni * 16 + (lane >> 4) * 4;
    float4 bb = *(const float4*)(bo + col);
    #pragma unroll
    for (int mi = 0; mi < 4; ++mi) {
      int row = m0 + wm0 + mi * 16 + (lane & 15);
      float4 wv4;
      wv4.x = acc[mi][ni][0] + bb.x;
      wv4.y = acc[mi][ni][1] + bb.y;
      wv4.z = acc[mi][ni][2] + bb.z;
      wv4.w = acc[mi][ni][3] + bb.w;
      *(float4*)(out + (size_t)row * 256 + col) = wv4;
    }
  }
}

extern "C" void kernel_launch(void* const* d_in, const int* in_sizes, int n_in,
                              void* d_out, int out_size, void* d_ws, size_t ws_size,
                              hipStream_t stream) {
  const float* x  = (const float*)d_in[0];
  const int* dist = (const int*)d_in[1];
  const float* Wq = (const float*)d_in[2];
  const float* bq = (const float*)d_in[3];
  const float* Wk = (const float*)d_in[4];
  const float* bk = (const float*)d_in[5];
  const float* Wv = (const float*)d_in[6];
  const float* bv = (const float*)d_in[7];
  const float* Wo = (const float*)d_in[8];
  const float* bo = (const float*)d_in[9];
  const float* rel = (const float*)d_in[10];
  float* out = (float*)d_out;
  float* probs = out + (size_t)SL;        // second output region (H,N,I,J) f32

  u16* ws = (u16*)d_ws;
  // slots: 0: lgt -> ct ; 1: qt -> pbf ; 2: kt -> vtt ; 3: vt
  u16* lgt = ws;
  u16* qt  = ws + (size_t)SL;
  u16* kt  = ws + (size_t)2 * SL;
  u16* vt  = ws + (size_t)3 * SL;
  u16* pbf = qt;
  u16* vtt = kt;
  u16* ctb = lgt;
  u16* Wb  = ws + (size_t)4 * SL;         // 4 x 65536 bf16 weights

  const float scaling = 0.022097086912079608f;   // 32^-0.5 / sqrt(64)

  k_castw  <<<128, 256, 0, stream>>>(Wq, Wk, Wv, Wo, Wb);
  k_proj_mm<<<2048, 256, 0, stream>>>(x, Wb, bq, bk, bv, qt, kt, vt, scaling);
  k_attn_mm<<<512, 256, 0, stream>>>(qt, kt, lgt);
  k_softmax<<<2048, 256, 0, stream>>>(lgt, dist, rel, probs, pbf);
  k_vtrans <<<8192, 256, 0, stream>>>(vt, vtt);
  k_ctx_mm <<<2048, 256, 0, stream>>>(vtt, pbf, ctb);
  k_oproj_mm<<<2048, 256, 0, stream>>>(ctb, Wb + 196608, bo, out);
}

// Round 9
// 362.945 us; speedup vs baseline: 1.0521x; 1.0521x over previous
//
#include <hip/hip_runtime.h>

typedef unsigned short u16;
typedef unsigned int u32;
typedef float f32x4 __attribute__((ext_vector_type(4)));
typedef short bf16x8 __attribute__((ext_vector_type(8)));
typedef unsigned short u16x8 __attribute__((ext_vector_type(8)));

#define SL 33554432u   // one 67MB slot, in u16 elements

__device__ __forceinline__ float bf2f(u16 u) {
  u32 v = ((u32)u) << 16;
  return __builtin_bit_cast(float, v);
}
__device__ __forceinline__ u16 f2bf(float f) {
  u32 i = __builtin_bit_cast(u32, f);
  i += 0x7fffu + ((i >> 16) & 1u);
  return (u16)(i >> 16);
}

#define GLDS16(g, l) __builtin_amdgcn_global_load_lds( \
    (const __attribute__((address_space(1))) void*)(g), \
    (__attribute__((address_space(3))) void*)(l), 16, 0, 0)

// ---- shared GEMM core: 128x128 tile, BK=64, 4 waves (2x2), bf16 MFMA ------
// A,B row-major with contiguous K (B^T form): C[m][n] = sum_k A[m][k]*B[n][k]
// LDS: linear dest (global_load_lds), global src pre-swizzled slot^(row&7).
// SWAP=false: col(lane&15)=B-row, reg-quad=4 consecutive A-rows.
// SWAP=true : col(lane&15)=A-row, reg-quad=4 consecutive B-rows.
__device__ __forceinline__ void stage128(const u16* gbase, int ldk, u16* lds, int tid) {
  #pragma unroll
  for (int rep = 0; rep < 4; ++rep) {
    int c = tid + rep * 256;            // chunk 0..1023
    int row = c >> 3, slot = c & 7;
    const u16* g = gbase + (size_t)row * ldk + ((slot ^ (row & 7)) << 3);
    GLDS16(g, lds + c * 8);
  }
}

template <bool SWAP>
__device__ __forceinline__ void mfma128(const u16* As, const u16* Bs, int lane,
                                        int wm0, int wn0, f32x4 acc[4][4]) {
  #pragma unroll
  for (int kk = 0; kk < 2; ++kk) {
    bf16x8 a[4], b[4];
    #pragma unroll
    for (int mi = 0; mi < 4; ++mi) {
      int r = wm0 + mi * 16 + (lane & 15);
      int c16 = (kk * 4 + (lane >> 4)) ^ (r & 7);
      a[mi] = *(const bf16x8*)(As + r * 64 + c16 * 8);
    }
    #pragma unroll
    for (int ni = 0; ni < 4; ++ni) {
      int r = wn0 + ni * 16 + (lane & 15);
      int c16 = (kk * 4 + (lane >> 4)) ^ (r & 7);
      b[ni] = *(const bf16x8*)(Bs + r * 64 + c16 * 8);
    }
    #pragma unroll
    for (int mi = 0; mi < 4; ++mi)
      #pragma unroll
      for (int ni = 0; ni < 4; ++ni)
        acc[mi][ni] = SWAP
          ? __builtin_amdgcn_mfma_f32_16x16x32_bf16(b[ni], a[mi], acc[mi][ni], 0, 0, 0)
          : __builtin_amdgcn_mfma_f32_16x16x32_bf16(a[mi], b[ni], acc[mi][ni], 0, 0, 0);
  }
}

template <bool SWAP>
__device__ __forceinline__ void gemm_core(const u16* A, int ldkA, const u16* B, int ldkB,
                                          int NT, u16* As, u16* Bs,
                                          int tid, int lane, int wm0, int wn0,
                                          f32x4 acc[4][4]) {
  for (int t = 0; t < NT; ++t) {
    stage128(A + t * 64, ldkA, As, tid);
    stage128(B + t * 64, ldkB, Bs, tid);
    __syncthreads();
    mfma128<SWAP>(As, Bs, lane, wm0, wn0, acc);
    __syncthreads();
  }
}

// ---------------- casts ----------------------------------------------------
__global__ __launch_bounds__(256) void k_castx(const float* __restrict__ src,
                                               u16* __restrict__ dst) {
  int idx = blockIdx.x * 256 + threadIdx.x;     // 4194304 chunks of 8
  const float4* s = (const float4*)src;
  float4 a = s[(size_t)idx * 2], b = s[(size_t)idx * 2 + 1];
  u16x8 o;
  o[0] = f2bf(a.x); o[1] = f2bf(a.y); o[2] = f2bf(a.z); o[3] = f2bf(a.w);
  o[4] = f2bf(b.x); o[5] = f2bf(b.y); o[6] = f2bf(b.z); o[7] = f2bf(b.w);
  *(u16x8*)(dst + (size_t)idx * 8) = o;
}

__global__ __launch_bounds__(256) void k_castw(
    const float* __restrict__ Wq, const float* __restrict__ Wk,
    const float* __restrict__ Wv, const float* __restrict__ Wo,
    u16* __restrict__ Wb) {
  int idx = blockIdx.x * 256 + threadIdx.x;     // 32768 chunks of 8
  int w = idx >> 13, off = idx & 8191;
  const float* src = (w == 0) ? Wq : (w == 1) ? Wk : (w == 2) ? Wv : Wo;
  const float4* s = (const float4*)(src + (size_t)off * 8);
  float4 a = s[0], b = s[1];
  u16x8 o;
  o[0] = f2bf(a.x); o[1] = f2bf(a.y); o[2] = f2bf(a.z); o[3] = f2bf(a.w);
  o[4] = f2bf(b.x); o[5] = f2bf(b.y); o[6] = f2bf(b.z); o[7] = f2bf(b.w);
  *(u16x8*)(Wb + (size_t)w * 65536 + (size_t)off * 8) = o;
}

// ---------------- K1: q/k/v projection GEMM (round-2 proven form) ----------
// grid (1024,2,3). A = xb [131072][256], B = W [256][256]. Scalar epilogue
// stores (proven: 32B L2-merged runs, WRITE exactly 201MB, 105.7us).
__global__ __launch_bounds__(256) void k_proj_mm(
    const u16* __restrict__ xb, const u16* __restrict__ Wb,
    const float* __restrict__ bq, const float* __restrict__ bk, const float* __restrict__ bv,
    u16* __restrict__ qt, u16* __restrict__ kt, u16* __restrict__ vt, float scaling) {
  __shared__ __align__(16) u16 As[128 * 64];
  __shared__ __align__(16) u16 Bs[128 * 64];
  const int tid = threadIdx.x, lane = tid & 63, wave = tid >> 6;
  const int wm0 = (wave >> 1) * 64, wn0 = (wave & 1) * 64;
  const int m0 = blockIdx.x * 128, n0 = blockIdx.y * 128, w = blockIdx.z;

  f32x4 acc[4][4];
  #pragma unroll
  for (int mi = 0; mi < 4; ++mi)
    #pragma unroll
    for (int ni = 0; ni < 4; ++ni) acc[mi][ni] = (f32x4){0.f, 0.f, 0.f, 0.f};

  gemm_core<false>(xb + (size_t)m0 * 256, 256, Wb + w * 65536 + (size_t)n0 * 256, 256,
                   4, As, Bs, tid, lane, wm0, wn0, acc);

  const float* bias = (w == 0) ? bq : (w == 1) ? bk : bv;
  u16* dst = (w == 0) ? qt : (w == 1) ? kt : vt;
  const float sc = (w == 0) ? scaling : 1.0f;

  #pragma unroll
  for (int mi = 0; mi < 4; ++mi)
    #pragma unroll
    for (int ni = 0; ni < 4; ++ni) {
      int f = n0 + wn0 + ni * 16 + (lane & 15);
      int h = f >> 5, d = f & 31;
      float bb = bias[f];
      #pragma unroll
      for (int q = 0; q < 4; ++q) {
        int m = m0 + wm0 + mi * 16 + (lane >> 4) * 4 + q;
        int n = m & 3, i = (m >> 2) & 511, r = m >> 11;
        size_t o = ((size_t)((n * 8 + h) * 512 + i)) * 2048 + r * 32 + d;
        dst[o] = f2bf((acc[mi][ni][q] + bb) * sc);
      }
    }
}

// ---------------- K2a: attention logits GEMM -------------------------------
// grid 512 = 32 nh x 16 tiles, XCD-swizzled. SWAPPED: reg-quad = 4 consecutive j.
__global__ __launch_bounds__(256) void k_attn_mm(
    const u16* __restrict__ qt, const u16* __restrict__ kt, u16* __restrict__ lgt) {
  __shared__ __align__(16) u16 As[128 * 64];
  __shared__ __align__(16) u16 Bs[128 * 64];
  const int tid = threadIdx.x, lane = tid & 63, wave = tid >> 6;
  const int wm0 = (wave >> 1) * 64, wn0 = (wave & 1) * 64;
  const int bid = blockIdx.x;
  const int sb = (bid & 7) * 64 + (bid >> 3);    // 512 % 8 == 0
  const int nh = sb >> 4, tt = sb & 15;
  const int m0 = (tt >> 2) * 128, n0 = (tt & 3) * 128;

  f32x4 acc[4][4];
  #pragma unroll
  for (int mi = 0; mi < 4; ++mi)
    #pragma unroll
    for (int ni = 0; ni < 4; ++ni) acc[mi][ni] = (f32x4){0.f, 0.f, 0.f, 0.f};

  const size_t base = (size_t)nh * 512 * 2048;
  gemm_core<true>(qt + base + (size_t)m0 * 2048, 2048, kt + base + (size_t)n0 * 2048, 2048,
                  32, As, Bs, tid, lane, wm0, wn0, acc);

  #pragma unroll
  for (int mi = 0; mi < 4; ++mi) {
    int row = m0 + wm0 + mi * 16 + (lane & 15);
    #pragma unroll
    for (int ni = 0; ni < 4; ++ni) {
      int col = n0 + wn0 + ni * 16 + (lane >> 4) * 4;
      ushort4 wv4;
      wv4.x = f2bf(acc[mi][ni][0]);
      wv4.y = f2bf(acc[mi][ni][1]);
      wv4.z = f2bf(acc[mi][ni][2]);
      wv4.w = f2bf(acc[mi][ni][3]);
      *(ushort4*)(lgt + (size_t)nh * 262144 + (size_t)row * 512 + col) = wv4;
    }
  }
}

// ---------------- K2b: bias + softmax (barrier-free, per-wave rows) --------
__global__ __launch_bounds__(256) void k_softmax(
    const u16* __restrict__ lgt, const int* __restrict__ dist, const float* __restrict__ rel,
    float* __restrict__ probs, u16* __restrict__ pbf) {
  const int t = threadIdx.x;
  const int lane = t & 63, wv = t >> 6;
  const int b = blockIdx.x;
  const int i = b & 511, n = b >> 9;

  const int* dr = dist + ((size_t)n * 512 + i) * 512 + lane * 8;
  int4 dA = *(const int4*)dr, dB = *(const int4*)(dr + 4);
  int dd[8] = {dA.x, dA.y, dA.z, dA.w, dB.x, dB.y, dB.z, dB.w};
  int u[8];
  #pragma unroll
  for (int j = 0; j < 8; ++j) {
    int v = dd[j] < 0 ? -dd[j] : dd[j];
    int q = (62 * v + 49999) / 50000; if (q > 63) q = 63;
    u[j] = q;
  }

  #pragma unroll
  for (int hh = 0; hh < 2; ++hh) {
    const int h = wv * 2 + hh;
    const int nh = n * 8 + h;
    const u16* lr = lgt + ((size_t)nh * 512 + i) * 512 + lane * 8;
    u16x8 L = *(const u16x8*)lr;
    float vj[8];
    float mx = -1e30f;
    #pragma unroll
    for (int j = 0; j < 8; ++j) {
      vj[j] = bf2f(L[j]) + rel[u[j] * 8 + h];
      mx = fmaxf(mx, vj[j]);
    }
    #pragma unroll
    for (int off = 32; off; off >>= 1) mx = fmaxf(mx, __shfl_xor(mx, off));
    float s = 0.f;
    #pragma unroll
    for (int j = 0; j < 8; ++j) { vj[j] = __expf(vj[j] - mx); s += vj[j]; }
    #pragma unroll
    for (int off = 32; off; off >>= 1) s += __shfl_xor(s, off);
    float inv = 1.0f / s;
    float4 pa, pb;
    pa.x = vj[0]*inv; pa.y = vj[1]*inv; pa.z = vj[2]*inv; pa.w = vj[3]*inv;
    pb.x = vj[4]*inv; pb.y = vj[5]*inv; pb.z = vj[6]*inv; pb.w = vj[7]*inv;
    size_t po = ((size_t)(h * 4 + n) * 512 + i) * 512 + lane * 8;
    *(float4*)(probs + po) = pa;
    *(float4*)(probs + po + 4) = pb;
    u16x8 pc;
    pc[0]=f2bf(pa.x); pc[1]=f2bf(pa.y); pc[2]=f2bf(pa.z); pc[3]=f2bf(pa.w);
    pc[4]=f2bf(pb.x); pc[5]=f2bf(pb.y); pc[6]=f2bf(pb.z); pc[7]=f2bf(pb.w);
    size_t pq = ((size_t)nh * 512 + i) * 512 + lane * 8;
    *(u16x8*)(pbf + pq) = pc;
  }
}

// ---------------- V transpose: vt [nh][i][c] -> vtt [nh][c][i] -------------
__global__ __launch_bounds__(256) void k_vtrans(const u16* __restrict__ vt, u16* __restrict__ vtt) {
  __shared__ u16 ts[64][72];
  const int b = blockIdx.x;             // nh*256 + it*32 + ct
  const int ct_ = b & 31, it = (b >> 5) & 7, nh = b >> 8;
  const int i0 = it * 64, c0 = ct_ * 64;
  const int t = threadIdx.x;
  #pragma unroll
  for (int rep = 0; rep < 2; ++rep) {
    int c = t + rep * 256;
    int r = c >> 3, q = c & 7;
    u16x8 v = *(const u16x8*)(vt + ((size_t)nh * 512 + i0 + r) * 2048 + c0 + q * 8);
    #pragma unroll
    for (int j = 0; j < 8; ++j) ts[r][q * 8 + j] = v[j];
  }
  __syncthreads();
  #pragma unroll
  for (int rep = 0; rep < 2; ++rep) {
    int c = t + rep * 256;
    int rr = c >> 3, q = c & 7;
    u16x8 o;
    #pragma unroll
    for (int j = 0; j < 8; ++j) o[j] = ts[q * 8 + j][rr];
    *(u16x8*)(vtt + ((size_t)nh * 2048 + c0 + rr) * 512 + i0 + q * 8) = o;
  }
}

// ---------------- K3: context GEMM (LDS-transpose epilogue, pad 130) -------
// grid 2048 = 32 nh x 64 tiles, XCD-swizzled. C tile = [c 128][i 128];
// epilogue transposes via LDS and writes 64B d-runs into ct x-layout.
__global__ __launch_bounds__(256) void k_ctx_mm(
    const u16* __restrict__ vtt, const u16* __restrict__ pbf, u16* __restrict__ ct) {
  __shared__ __align__(16) u16 lds[16640];      // staging 16384 U ts 128*130
  u16* As = lds;
  u16* Bs = lds + 8192;
  u16* ts = lds;
  const int tid = threadIdx.x, lane = tid & 63, wave = tid >> 6;
  const int wm0 = (wave >> 1) * 64, wn0 = (wave & 1) * 64;
  const int bid = blockIdx.x;
  const int sb = (bid & 7) * 256 + (bid >> 3);   // 2048 % 8 == 0
  const int nh = sb >> 6, tt = sb & 63;
  const int m0 = (tt >> 2) * 128, n0 = (tt & 3) * 128;
  const int n = nh >> 3, h = nh & 7;

  f32x4 acc[4][4];
  #pragma unroll
  for (int mi = 0; mi < 4; ++mi)
    #pragma unroll
    for (int ni = 0; ni < 4; ++ni) acc[mi][ni] = (f32x4){0.f, 0.f, 0.f, 0.f};

  gemm_core<false>(vtt + (size_t)nh * 1048576 + (size_t)m0 * 512, 512,
                   pbf + (size_t)nh * 262144 + (size_t)n0 * 512, 512,
                   8, As, Bs, tid, lane, wm0, wn0, acc);

  // ts[i_local][c_local], pad 130
  #pragma unroll
  for (int mi = 0; mi < 4; ++mi)
    #pragma unroll
    for (int ni = 0; ni < 4; ++ni) {
      int i_l = wn0 + ni * 16 + (lane & 15);
      #pragma unroll
      for (int q = 0; q < 4; ++q) {
        int c_l = wm0 + mi * 16 + (lane >> 4) * 4 + q;
        ts[i_l * 130 + c_l] = f2bf(acc[mi][ni][q]);
      }
    }
  __syncthreads();
  #pragma unroll
  for (int cc = 0; cc < 2; ++cc) {
    int ch = tid + cc * 256;
    int i_l = ch & 127, r_l = ch >> 7;
    const u16* src = ts + i_l * 130 + r_l * 32;
    int rr = (m0 >> 5) + r_l;
    size_t o = ((size_t)((rr * 512 + n0 + i_l) * 4 + n)) * 256 + h * 32;
    #pragma unroll
    for (int j = 0; j < 4; ++j)
      *(u16x8*)(ct + o + j * 8) = *(const u16x8*)(src + j * 8);
  }
}

// ---------------- K4: output projection GEMM -------------------------------
// SWAPPED: reg-quad = 4 consecutive cols -> float4 stores.
__global__ __launch_bounds__(256) void k_oproj_mm(
    const u16* __restrict__ ct, const u16* __restrict__ Wob,
    const float* __restrict__ bo, float* __restrict__ out) {
  __shared__ __align__(16) u16 As[128 * 64];
  __shared__ __align__(16) u16 Bs[128 * 64];
  const int tid = threadIdx.x, lane = tid & 63, wave = tid >> 6;
  const int wm0 = (wave >> 1) * 64, wn0 = (wave & 1) * 64;
  const int bid = blockIdx.x;
  const int sb = (bid & 7) * 256 + (bid >> 3);
  const int m0 = (sb >> 1) * 128, n0 = (sb & 1) * 128;

  f32x4 acc[4][4];
  #pragma unroll
  for (int mi = 0; mi < 4; ++mi)
    #pragma unroll
    for (int ni = 0; ni < 4; ++ni) acc[mi][ni] = (f32x4){0.f, 0.f, 0.f, 0.f};

  gemm_core<true>(ct + (size_t)m0 * 256, 256, Wob + (size_t)n0 * 256, 256,
                  4, As, Bs, tid, lane, wm0, wn0, acc);

  #pragma unroll
  for (int ni = 0; ni < 4; ++ni) {
    int col = n0 + wn0 + ni * 16 + (lane >> 4) * 4;
    float4 bb = *(const float4*)(bo + col);
    #pragma unroll
    for (int mi = 0; mi < 4; ++mi) {
      int row = m0 + wm0 + mi * 16 + (lane & 15);
      float4 wv4;
      wv4.x = acc[mi][ni][0] + bb.x;
      wv4.y = acc[mi][ni][1] + bb.y;
      wv4.z = acc[mi][ni][2] + bb.z;
      wv4.w = acc[mi][ni][3] + bb.w;
      *(float4*)(out + (size_t)row * 256 + col) = wv4;
    }
  }
}

extern "C" void kernel_launch(void* const* d_in, const int* in_sizes, int n_in,
                              void* d_out, int out_size, void* d_ws, size_t ws_size,
                              hipStream_t stream) {
  const float* x  = (const float*)d_in[0];
  const int* dist = (const int*)d_in[1];
  const float* Wq = (const float*)d_in[2];
  const float* bq = (const float*)d_in[3];
  const float* Wk = (const float*)d_in[4];
  const float* bk = (const float*)d_in[5];
  const float* Wv = (const float*)d_in[6];
  const float* bv = (const float*)d_in[7];
  const float* Wo = (const float*)d_in[8];
  const float* bo = (const float*)d_in[9];
  const float* rel = (const float*)d_in[10];
  float* out = (float*)d_out;
  float* probs = out + (size_t)SL;        // second output region (H,N,I,J) f32

  u16* ws = (u16*)d_ws;
  // slots: 0: xb -> lgt -> ct ; 1: qt -> pbf ; 2: kt -> vtt ; 3: vt
  u16* xb  = ws;
  u16* qt  = ws + (size_t)SL;
  u16* kt  = ws + (size_t)2 * SL;
  u16* vt  = ws + (size_t)3 * SL;
  u16* lgt = xb;
  u16* pbf = qt;
  u16* vtt = kt;
  u16* ctb = xb;
  u16* Wb  = ws + (size_t)4 * SL;         // 4 x 65536 bf16 weights

  const float scaling = 0.022097086912079608f;   // 32^-0.5 / sqrt(64)

  k_castx  <<<16384, 256, 0, stream>>>(x, xb);
  k_castw  <<<128, 256, 0, stream>>>(Wq, Wk, Wv, Wo, Wb);
  k_proj_mm<<<dim3(1024, 2, 3), 256, 0, stream>>>(xb, Wb, bq, bk, bv, qt, kt, vt, scaling);
  k_attn_mm<<<512, 256, 0, stream>>>(qt, kt, lgt);
  k_softmax<<<2048, 256, 0, stream>>>(lgt, dist, rel, probs, pbf);
  k_vtrans <<<8192, 256, 0, stream>>>(vt, vtt);
  k_ctx_mm <<<2048, 256, 0, stream>>>(vtt, pbf, ctb);
  k_oproj_mm<<<2048, 256, 0, stream>>>(ctb, Wb + 196608, bo, out);
}

// Round 10
// 360.968 us; speedup vs baseline: 1.0579x; 1.0055x over previous
//
#include <hip/hip_runtime.h>

typedef unsigned short u16;
typedef unsigned int u32;
typedef float f32x4 __attribute__((ext_vector_type(4)));
typedef short bf16x8 __attribute__((ext_vector_type(8)));
typedef unsigned short u16x8 __attribute__((ext_vector_type(8)));

#define SL 33554432u   // one 67MB slot, in u16 elements

__device__ __forceinline__ float bf2f(u16 u) {
  u32 v = ((u32)u) << 16;
  return __builtin_bit_cast(float, v);
}
__device__ __forceinline__ u16 f2bf(float f) {
  u32 i = __builtin_bit_cast(u32, f);
  i += 0x7fffu + ((i >> 16) & 1u);
  return (u16)(i >> 16);
}

#define GLDS16(g, l) __builtin_amdgcn_global_load_lds( \
    (const __attribute__((address_space(1))) void*)(g), \
    (__attribute__((address_space(3))) void*)(l), 16, 0, 0)

// ---- shared GEMM core: 128x128 tile, BK=64, 4 waves (2x2), bf16 MFMA ------
// A,B row-major with contiguous K (B^T form): C[m][n] = sum_k A[m][k]*B[n][k]
// LDS: linear dest (global_load_lds), global src pre-swizzled slot^(row&7).
// C/D map: col(lane&15)=B-row, reg-quad=4 consecutive A-rows (m89/m91).
__device__ __forceinline__ void stage128(const u16* gbase, int ldk, u16* lds, int tid) {
  #pragma unroll
  for (int rep = 0; rep < 4; ++rep) {
    int c = tid + rep * 256;            // chunk 0..1023
    int row = c >> 3, slot = c & 7;
    const u16* g = gbase + (size_t)row * ldk + ((slot ^ (row & 7)) << 3);
    GLDS16(g, lds + c * 8);
  }
}

__device__ __forceinline__ void mfma128(const u16* As, const u16* Bs, int lane,
                                        int wm0, int wn0, f32x4 acc[4][4]) {
  #pragma unroll
  for (int kk = 0; kk < 2; ++kk) {
    bf16x8 a[4], b[4];
    #pragma unroll
    for (int mi = 0; mi < 4; ++mi) {
      int r = wm0 + mi * 16 + (lane & 15);
      int c16 = (kk * 4 + (lane >> 4)) ^ (r & 7);
      a[mi] = *(const bf16x8*)(As + r * 64 + c16 * 8);
    }
    #pragma unroll
    for (int ni = 0; ni < 4; ++ni) {
      int r = wn0 + ni * 16 + (lane & 15);
      int c16 = (kk * 4 + (lane >> 4)) ^ (r & 7);
      b[ni] = *(const bf16x8*)(Bs + r * 64 + c16 * 8);
    }
    #pragma unroll
    for (int mi = 0; mi < 4; ++mi)
      #pragma unroll
      for (int ni = 0; ni < 4; ++ni)
        acc[mi][ni] = __builtin_amdgcn_mfma_f32_16x16x32_bf16(a[mi], b[ni], acc[mi][ni], 0, 0, 0);
  }
}

__device__ __forceinline__ void gemm_core(const u16* A, int ldkA, const u16* B, int ldkB,
                                          int NT, u16* As, u16* Bs,
                                          int tid, int lane, int wm0, int wn0,
                                          f32x4 acc[4][4]) {
  for (int t = 0; t < NT; ++t) {
    stage128(A + t * 64, ldkA, As, tid);
    stage128(B + t * 64, ldkB, Bs, tid);
    __syncthreads();
    mfma128(As, Bs, lane, wm0, wn0, acc);
    __syncthreads();
  }
}

// ---------------- casts ----------------------------------------------------
__global__ __launch_bounds__(256) void k_castx(const float* __restrict__ src,
                                               u16* __restrict__ dst) {
  int idx = blockIdx.x * 256 + threadIdx.x;     // 4194304 chunks of 8
  const float4* s = (const float4*)src;
  float4 a = s[(size_t)idx * 2], b = s[(size_t)idx * 2 + 1];
  u16x8 o;
  o[0] = f2bf(a.x); o[1] = f2bf(a.y); o[2] = f2bf(a.z); o[3] = f2bf(a.w);
  o[4] = f2bf(b.x); o[5] = f2bf(b.y); o[6] = f2bf(b.z); o[7] = f2bf(b.w);
  *(u16x8*)(dst + (size_t)idx * 8) = o;
}

__global__ __launch_bounds__(256) void k_castw(
    const float* __restrict__ Wq, const float* __restrict__ Wk,
    const float* __restrict__ Wv, const float* __restrict__ Wo,
    u16* __restrict__ Wb) {
  int idx = blockIdx.x * 256 + threadIdx.x;     // 32768 chunks of 8
  int w = idx >> 13, off = idx & 8191;
  const float* src = (w == 0) ? Wq : (w == 1) ? Wk : (w == 2) ? Wv : Wo;
  const float4* s = (const float4*)(src + (size_t)off * 8);
  float4 a = s[0], b = s[1];
  u16x8 o;
  o[0] = f2bf(a.x); o[1] = f2bf(a.y); o[2] = f2bf(a.z); o[3] = f2bf(a.w);
  o[4] = f2bf(b.x); o[5] = f2bf(b.y); o[6] = f2bf(b.z); o[7] = f2bf(b.w);
  *(u16x8*)(Wb + (size_t)w * 65536 + (size_t)off * 8) = o;
}

// ---------------- K1: q/k/v projection GEMM (round-2 proven form) ----------
// grid (1024,2,3). A = xb [131072][256], B = W [256][256]. Scalar epilogue
// stores (proven: 32B L2-merged runs, WRITE exactly 201MB, ~106us).
__global__ __launch_bounds__(256) void k_proj_mm(
    const u16* __restrict__ xb, const u16* __restrict__ Wb,
    const float* __restrict__ bq, const float* __restrict__ bk, const float* __restrict__ bv,
    u16* __restrict__ qt, u16* __restrict__ kt, u16* __restrict__ vt, float scaling) {
  __shared__ __align__(16) u16 As[128 * 64];
  __shared__ __align__(16) u16 Bs[128 * 64];
  const int tid = threadIdx.x, lane = tid & 63, wave = tid >> 6;
  const int wm0 = (wave >> 1) * 64, wn0 = (wave & 1) * 64;
  const int m0 = blockIdx.x * 128, n0 = blockIdx.y * 128, w = blockIdx.z;

  f32x4 acc[4][4];
  #pragma unroll
  for (int mi = 0; mi < 4; ++mi)
    #pragma unroll
    for (int ni = 0; ni < 4; ++ni) acc[mi][ni] = (f32x4){0.f, 0.f, 0.f, 0.f};

  gemm_core(xb + (size_t)m0 * 256, 256, Wb + w * 65536 + (size_t)n0 * 256, 256,
            4, As, Bs, tid, lane, wm0, wn0, acc);

  const float* bias = (w == 0) ? bq : (w == 1) ? bk : bv;
  u16* dst = (w == 0) ? qt : (w == 1) ? kt : vt;
  const float sc = (w == 0) ? scaling : 1.0f;

  #pragma unroll
  for (int mi = 0; mi < 4; ++mi)
    #pragma unroll
    for (int ni = 0; ni < 4; ++ni) {
      int f = n0 + wn0 + ni * 16 + (lane & 15);
      int h = f >> 5, d = f & 31;
      float bb = bias[f];
      #pragma unroll
      for (int q = 0; q < 4; ++q) {
        int m = m0 + wm0 + mi * 16 + (lane >> 4) * 4 + q;
        int n = m & 3, i = (m >> 2) & 511, r = m >> 11;
        size_t o = ((size_t)((n * 8 + h) * 512 + i)) * 2048 + r * 32 + d;
        dst[o] = f2bf((acc[mi][ni][q] + bb) * sc);
      }
    }
}

// ---------------- K2a: attention logits GEMM (round-5 proven form) ---------
// grid 512 = 32 nh x 16 tiles, XCD-swizzled. Scalar epilogue stores.
__global__ __launch_bounds__(256) void k_attn_mm(
    const u16* __restrict__ qt, const u16* __restrict__ kt, u16* __restrict__ lgt) {
  __shared__ __align__(16) u16 As[128 * 64];
  __shared__ __align__(16) u16 Bs[128 * 64];
  const int tid = threadIdx.x, lane = tid & 63, wave = tid >> 6;
  const int wm0 = (wave >> 1) * 64, wn0 = (wave & 1) * 64;
  const int bid = blockIdx.x;
  const int sb = (bid & 7) * 64 + (bid >> 3);    // 512 % 8 == 0
  const int nh = sb >> 4, tt = sb & 15;
  const int m0 = (tt >> 2) * 128, n0 = (tt & 3) * 128;

  f32x4 acc[4][4];
  #pragma unroll
  for (int mi = 0; mi < 4; ++mi)
    #pragma unroll
    for (int ni = 0; ni < 4; ++ni) acc[mi][ni] = (f32x4){0.f, 0.f, 0.f, 0.f};

  const size_t base = (size_t)nh * 512 * 2048;
  gemm_core(qt + base + (size_t)m0 * 2048, 2048, kt + base + (size_t)n0 * 2048, 2048,
            32, As, Bs, tid, lane, wm0, wn0, acc);

  #pragma unroll
  for (int mi = 0; mi < 4; ++mi)
    #pragma unroll
    for (int ni = 0; ni < 4; ++ni) {
      int col = n0 + wn0 + ni * 16 + (lane & 15);
      #pragma unroll
      for (int q = 0; q < 4; ++q) {
        int row = m0 + wm0 + mi * 16 + (lane >> 4) * 4 + q;
        lgt[(size_t)nh * 262144 + (size_t)row * 512 + col] = f2bf(acc[mi][ni][q]);
      }
    }
}

// ---------------- K2b: bias + softmax (barrier-free, per-wave rows) --------
__global__ __launch_bounds__(256) void k_softmax(
    const u16* __restrict__ lgt, const int* __restrict__ dist, const float* __restrict__ rel,
    float* __restrict__ probs, u16* __restrict__ pbf) {
  const int t = threadIdx.x;
  const int lane = t & 63, wv = t >> 6;
  const int b = blockIdx.x;
  const int i = b & 511, n = b >> 9;

  const int* dr = dist + ((size_t)n * 512 + i) * 512 + lane * 8;
  int4 dA = *(const int4*)dr, dB = *(const int4*)(dr + 4);
  int dd[8] = {dA.x, dA.y, dA.z, dA.w, dB.x, dB.y, dB.z, dB.w};
  int u[8];
  #pragma unroll
  for (int j = 0; j < 8; ++j) {
    int v = dd[j] < 0 ? -dd[j] : dd[j];
    int q = (62 * v + 49999) / 50000; if (q > 63) q = 63;
    u[j] = q;
  }

  #pragma unroll
  for (int hh = 0; hh < 2; ++hh) {
    const int h = wv * 2 + hh;
    const int nh = n * 8 + h;
    const u16* lr = lgt + ((size_t)nh * 512 + i) * 512 + lane * 8;
    u16x8 L = *(const u16x8*)lr;
    float vj[8];
    float mx = -1e30f;
    #pragma unroll
    for (int j = 0; j < 8; ++j) {
      vj[j] = bf2f(L[j]) + rel[u[j] * 8 + h];
      mx = fmaxf(mx, vj[j]);
    }
    #pragma unroll
    for (int off = 32; off; off >>= 1) mx = fmaxf(mx, __shfl_xor(mx, off));
    float s = 0.f;
    #pragma unroll
    for (int j = 0; j < 8; ++j) { vj[j] = __expf(vj[j] - mx); s += vj[j]; }
    #pragma unroll
    for (int off = 32; off; off >>= 1) s += __shfl_xor(s, off);
    float inv = 1.0f / s;
    float4 pa, pb;
    pa.x = vj[0]*inv; pa.y = vj[1]*inv; pa.z = vj[2]*inv; pa.w = vj[3]*inv;
    pb.x = vj[4]*inv; pb.y = vj[5]*inv; pb.z = vj[6]*inv; pb.w = vj[7]*inv;
    size_t po = ((size_t)(h * 4 + n) * 512 + i) * 512 + lane * 8;
    *(float4*)(probs + po) = pa;
    *(float4*)(probs + po + 4) = pb;
    u16x8 pc;
    pc[0]=f2bf(pa.x); pc[1]=f2bf(pa.y); pc[2]=f2bf(pa.z); pc[3]=f2bf(pa.w);
    pc[4]=f2bf(pb.x); pc[5]=f2bf(pb.y); pc[6]=f2bf(pb.z); pc[7]=f2bf(pb.w);
    size_t pq = ((size_t)nh * 512 + i) * 512 + lane * 8;
    *(u16x8*)(pbf + pq) = pc;
  }
}

// ---------------- V transpose: vt [nh][i][c] -> vtt [nh][c][i] -------------
__global__ __launch_bounds__(256) void k_vtrans(const u16* __restrict__ vt, u16* __restrict__ vtt) {
  __shared__ u16 ts[64][72];
  const int b = blockIdx.x;             // nh*256 + it*32 + ct
  const int ct_ = b & 31, it = (b >> 5) & 7, nh = b >> 8;
  const int i0 = it * 64, c0 = ct_ * 64;
  const int t = threadIdx.x;
  #pragma unroll
  for (int rep = 0; rep < 2; ++rep) {
    int c = t + rep * 256;
    int r = c >> 3, q = c & 7;
    u16x8 v = *(const u16x8*)(vt + ((size_t)nh * 512 + i0 + r) * 2048 + c0 + q * 8);
    #pragma unroll
    for (int j = 0; j < 8; ++j) ts[r][q * 8 + j] = v[j];
  }
  __syncthreads();
  #pragma unroll
  for (int rep = 0; rep < 2; ++rep) {
    int c = t + rep * 256;
    int rr = c >> 3, q = c & 7;
    u16x8 o;
    #pragma unroll
    for (int j = 0; j < 8; ++j) o[j] = ts[q * 8 + j][rr];
    *(u16x8*)(vtt + ((size_t)nh * 2048 + c0 + rr) * 512 + i0 + q * 8) = o;
  }
}

// ---------------- K3: context GEMM (LDS-transpose epilogue, pad 130) -------
// grid 2048 = 32 nh x 64 tiles, XCD-swizzled. C tile = [c 128][i 128];
// epilogue transposes via LDS and writes 64B d-runs into ct x-layout.
__global__ __launch_bounds__(256) void k_ctx_mm(
    const u16* __restrict__ vtt, const u16* __restrict__ pbf, u16* __restrict__ ct) {
  __shared__ __align__(16) u16 lds[16640];      // staging 16384 U ts 128*130
  u16* As = lds;
  u16* Bs = lds + 8192;
  u16* ts = lds;
  const int tid = threadIdx.x, lane = tid & 63, wave = tid >> 6;
  const int wm0 = (wave >> 1) * 64, wn0 = (wave & 1) * 64;
  const int bid = blockIdx.x;
  const int sb = (bid & 7) * 256 + (bid >> 3);   // 2048 % 8 == 0
  const int nh = sb >> 6, tt = sb & 63;
  const int m0 = (tt >> 2) * 128, n0 = (tt & 3) * 128;
  const int n = nh >> 3, h = nh & 7;

  f32x4 acc[4][4];
  #pragma unroll
  for (int mi = 0; mi < 4; ++mi)
    #pragma unroll
    for (int ni = 0; ni < 4; ++ni) acc[mi][ni] = (f32x4){0.f, 0.f, 0.f, 0.f};

  gemm_core(vtt + (size_t)nh * 1048576 + (size_t)m0 * 512, 512,
            pbf + (size_t)nh * 262144 + (size_t)n0 * 512, 512,
            8, As, Bs, tid, lane, wm0, wn0, acc);

  // ts[i_local][c_local], pad 130
  #pragma unroll
  for (int mi = 0; mi < 4; ++mi)
    #pragma unroll
    for (int ni = 0; ni < 4; ++ni) {
      int i_l = wn0 + ni * 16 + (lane & 15);
      #pragma unroll
      for (int q = 0; q < 4; ++q) {
        int c_l = wm0 + mi * 16 + (lane >> 4) * 4 + q;
        ts[i_l * 130 + c_l] = f2bf(acc[mi][ni][q]);
      }
    }
  __syncthreads();
  #pragma unroll
  for (int cc = 0; cc < 2; ++cc) {
    int ch = tid + cc * 256;
    int i_l = ch & 127, r_l = ch >> 7;
    const u16* src = ts + i_l * 130 + r_l * 32;
    int rr = (m0 >> 5) + r_l;
    size_t o = ((size_t)((rr * 512 + n0 + i_l) * 4 + n)) * 256 + h * 32;
    #pragma unroll
    for (int j = 0; j < 4; ++j)
      *(u16x8*)(ct + o + j * 8) = *(const u16x8*)(src + j * 8);
  }
}

// ---------------- K4: output projection GEMM (round-5 proven form) ---------
// grid 2048, XCD-swizzled. Scalar f32 epilogue stores.
__global__ __launch_bounds__(256) void k_oproj_mm(
    const u16* __restrict__ ct, const u16* __restrict__ Wob,
    const float* __restrict__ bo, float* __restrict__ out) {
  __shared__ __align__(16) u16 As[128 * 64];
  __shared__ __align__(16) u16 Bs[128 * 64];
  const int tid = threadIdx.x, lane = tid & 63, wave = tid >> 6;
  const int wm0 = (wave >> 1) * 64, wn0 = (wave & 1) * 64;
  const int bid = blockIdx.x;
  const int sb = (bid & 7) * 256 + (bid >> 3);
  const int m0 = (sb >> 1) * 128, n0 = (sb & 1) * 128;

  f32x4 acc[4][4];
  #pragma unroll
  for (int mi = 0; mi < 4; ++mi)
    #pragma unroll
    for (int ni = 0; ni < 4; ++ni) acc[mi][ni] = (f32x4){0.f, 0.f, 0.f, 0.f};

  gemm_core(ct + (size_t)m0 * 256, 256, Wob + (size_t)n0 * 256, 256,
            4, As, Bs, tid, lane, wm0, wn0, acc);

  #pragma unroll
  for (int mi = 0; mi < 4; ++mi)
    #pragma unroll
    for (int ni = 0; ni < 4; ++ni) {
      int col = n0 + wn0 + ni * 16 + (lane & 15);
      float bb = bo[col];
      #pragma unroll
      for (int q = 0; q < 4; ++q) {
        int row = m0 + wm0 + mi * 16 + (lane >> 4) * 4 + q;
        out[(size_t)row * 256 + col] = acc[mi][ni][q] + bb;
      }
    }
}

extern "C" void kernel_launch(void* const* d_in, const int* in_sizes, int n_in,
                              void* d_out, int out_size, void* d_ws, size_t ws_size,
                              hipStream_t stream) {
  const float* x  = (const float*)d_in[0];
  const int* dist = (const int*)d_in[1];
  const float* Wq = (const float*)d_in[2];
  const float* bq = (const float*)d_in[3];
  const float* Wk = (const float*)d_in[4];
  const float* bk = (const float*)d_in[5];
  const float* Wv = (const float*)d_in[6];
  const float* bv = (const float*)d_in[7];
  const float* Wo = (const float*)d_in[8];
  const float* bo = (const float*)d_in[9];
  const float* rel = (const float*)d_in[10];
  float* out = (float*)d_out;
  float* probs = out + (size_t)SL;        // second output region (H,N,I,J) f32

  u16* ws = (u16*)d_ws;
  // slots: 0: xb -> lgt -> ct ; 1: qt -> pbf ; 2: kt -> vtt ; 3: vt
  u16* xb  = ws;
  u16* qt  = ws + (size_t)SL;
  u16* kt  = ws + (size_t)2 * SL;
  u16* vt  = ws + (size_t)3 * SL;
  u16* lgt = xb;
  u16* pbf = qt;
  u16* vtt = kt;
  u16* ctb = xb;
  u16* Wb  = ws + (size_t)4 * SL;         // 4 x 65536 bf16 weights

  const float scaling = 0.022097086912079608f;   // 32^-0.5 / sqrt(64)

  k_castx  <<<16384, 256, 0, stream>>>(x, xb);
  k_castw  <<<128, 256, 0, stream>>>(Wq, Wk, Wv, Wo, Wb);
  k_proj_mm<<<dim3(1024, 2, 3), 256, 0, stream>>>(xb, Wb, bq, bk, bv, qt, kt, vt, scaling);
  k_attn_mm<<<512, 256, 0, stream>>>(qt, kt, lgt);
  k_softmax<<<2048, 256, 0, stream>>>(lgt, dist, rel, probs, pbf);
  k_vtrans <<<8192, 256, 0, stream>>>(vt, vtt);
  k_ctx_mm <<<2048, 256, 0, stream>>>(vtt, pbf, ctb);
  k_oproj_mm<<<2048, 256, 0, stream>>>(ctb, Wb + 196608, bo, out);
}

// Round 11
// 358.610 us; speedup vs baseline: 1.0649x; 1.0066x over previous
//
#include <hip/hip_runtime.h>

typedef unsigned short u16;
typedef unsigned int u32;
typedef float f32x4 __attribute__((ext_vector_type(4)));
typedef short bf16x8 __attribute__((ext_vector_type(8)));
typedef unsigned short u16x8 __attribute__((ext_vector_type(8)));

#define SL 33554432u   // one 67MB slot, in u16 elements

__device__ __forceinline__ float bf2f(u16 u) {
  u32 v = ((u32)u) << 16;
  return __builtin_bit_cast(float, v);
}
__device__ __forceinline__ u16 f2bf(float f) {
  u32 i = __builtin_bit_cast(u32, f);
  i += 0x7fffu + ((i >> 16) & 1u);
  return (u16)(i >> 16);
}

#define GLDS16(g, l) __builtin_amdgcn_global_load_lds( \
    (const __attribute__((address_space(1))) void*)(g), \
    (__attribute__((address_space(3))) void*)(l), 16, 0, 0)

// ==== 256-thread (4-wave) GEMM core — used by ctx/oproj (proven) ===========
__device__ __forceinline__ void stage128(const u16* gbase, int ldk, u16* lds, int tid) {
  #pragma unroll
  for (int rep = 0; rep < 4; ++rep) {
    int c = tid + rep * 256;            // chunk 0..1023
    int row = c >> 3, slot = c & 7;
    const u16* g = gbase + (size_t)row * ldk + ((slot ^ (row & 7)) << 3);
    GLDS16(g, lds + c * 8);
  }
}

__device__ __forceinline__ void mfma128(const u16* As, const u16* Bs, int lane,
                                        int wm0, int wn0, f32x4 acc[4][4]) {
  #pragma unroll
  for (int kk = 0; kk < 2; ++kk) {
    bf16x8 a[4], b[4];
    #pragma unroll
    for (int mi = 0; mi < 4; ++mi) {
      int r = wm0 + mi * 16 + (lane & 15);
      int c16 = (kk * 4 + (lane >> 4)) ^ (r & 7);
      a[mi] = *(const bf16x8*)(As + r * 64 + c16 * 8);
    }
    #pragma unroll
    for (int ni = 0; ni < 4; ++ni) {
      int r = wn0 + ni * 16 + (lane & 15);
      int c16 = (kk * 4 + (lane >> 4)) ^ (r & 7);
      b[ni] = *(const bf16x8*)(Bs + r * 64 + c16 * 8);
    }
    #pragma unroll
    for (int mi = 0; mi < 4; ++mi)
      #pragma unroll
      for (int ni = 0; ni < 4; ++ni)
        acc[mi][ni] = __builtin_amdgcn_mfma_f32_16x16x32_bf16(a[mi], b[ni], acc[mi][ni], 0, 0, 0);
  }
}

__device__ __forceinline__ void gemm_core(const u16* A, int ldkA, const u16* B, int ldkB,
                                          int NT, u16* As, u16* Bs,
                                          int tid, int lane, int wm0, int wn0,
                                          f32x4 acc[4][4]) {
  for (int t = 0; t < NT; ++t) {
    stage128(A + t * 64, ldkA, As, tid);
    stage128(B + t * 64, ldkB, Bs, tid);
    __syncthreads();
    mfma128(As, Bs, lane, wm0, wn0, acc);
    __syncthreads();
  }
}

// ==== 512-thread (8-wave) GEMM core — proj/attn occupancy fix ==============
// Same 128x128 tile & LDS layout; wave grid 2M x 4N, per-wave 64x32 output.
__device__ __forceinline__ void stage128_512(const u16* gbase, int ldk, u16* lds, int tid) {
  #pragma unroll
  for (int rep = 0; rep < 2; ++rep) {
    int c = tid + rep * 512;            // chunk 0..1023
    int row = c >> 3, slot = c & 7;
    const u16* g = gbase + (size_t)row * ldk + ((slot ^ (row & 7)) << 3);
    GLDS16(g, lds + c * 8);
  }
}

__device__ __forceinline__ void mfma128_8w(const u16* As, const u16* Bs, int lane,
                                           int wm0, int wn0, f32x4 acc[4][2]) {
  #pragma unroll
  for (int kk = 0; kk < 2; ++kk) {
    bf16x8 a[4], b[2];
    #pragma unroll
    for (int mi = 0; mi < 4; ++mi) {
      int r = wm0 + mi * 16 + (lane & 15);
      int c16 = (kk * 4 + (lane >> 4)) ^ (r & 7);
      a[mi] = *(const bf16x8*)(As + r * 64 + c16 * 8);
    }
    #pragma unroll
    for (int ni = 0; ni < 2; ++ni) {
      int r = wn0 + ni * 16 + (lane & 15);
      int c16 = (kk * 4 + (lane >> 4)) ^ (r & 7);
      b[ni] = *(const bf16x8*)(Bs + r * 64 + c16 * 8);
    }
    #pragma unroll
    for (int mi = 0; mi < 4; ++mi)
      #pragma unroll
      for (int ni = 0; ni < 2; ++ni)
        acc[mi][ni] = __builtin_amdgcn_mfma_f32_16x16x32_bf16(a[mi], b[ni], acc[mi][ni], 0, 0, 0);
  }
}

__device__ __forceinline__ void gemm_core_512(const u16* A, int ldkA, const u16* B, int ldkB,
                                              int NT, u16* As, u16* Bs,
                                              int tid, int lane, int wm0, int wn0,
                                              f32x4 acc[4][2]) {
  for (int t = 0; t < NT; ++t) {
    stage128_512(A + t * 64, ldkA, As, tid);
    stage128_512(B + t * 64, ldkB, Bs, tid);
    __syncthreads();
    mfma128_8w(As, Bs, lane, wm0, wn0, acc);
    __syncthreads();
  }
}

// ---------------- casts ----------------------------------------------------
__global__ __launch_bounds__(256) void k_castx(const float* __restrict__ src,
                                               u16* __restrict__ dst) {
  int idx = blockIdx.x * 256 + threadIdx.x;     // 4194304 chunks of 8
  const float4* s = (const float4*)src;
  float4 a = s[(size_t)idx * 2], b = s[(size_t)idx * 2 + 1];
  u16x8 o;
  o[0] = f2bf(a.x); o[1] = f2bf(a.y); o[2] = f2bf(a.z); o[3] = f2bf(a.w);
  o[4] = f2bf(b.x); o[5] = f2bf(b.y); o[6] = f2bf(b.z); o[7] = f2bf(b.w);
  *(u16x8*)(dst + (size_t)idx * 8) = o;
}

__global__ __launch_bounds__(256) void k_castw(
    const float* __restrict__ Wq, const float* __restrict__ Wk,
    const float* __restrict__ Wv, const float* __restrict__ Wo,
    u16* __restrict__ Wb) {
  int idx = blockIdx.x * 256 + threadIdx.x;     // 32768 chunks of 8
  int w = idx >> 13, off = idx & 8191;
  const float* src = (w == 0) ? Wq : (w == 1) ? Wk : (w == 2) ? Wv : Wo;
  const float4* s = (const float4*)(src + (size_t)off * 8);
  float4 a = s[0], b = s[1];
  u16x8 o;
  o[0] = f2bf(a.x); o[1] = f2bf(a.y); o[2] = f2bf(a.z); o[3] = f2bf(a.w);
  o[4] = f2bf(b.x); o[5] = f2bf(b.y); o[6] = f2bf(b.z); o[7] = f2bf(b.w);
  *(u16x8*)(Wb + (size_t)w * 65536 + (size_t)off * 8) = o;
}

// ---------------- K1: q/k/v projection GEMM (8-wave variant) ---------------
// grid (1024,2,3), 512 threads. Same tiles/traffic as the proven r2 form;
// 8 waves/block doubles waves/CU to hide the per-K-tile barrier drain.
__global__ __launch_bounds__(512) void k_proj_mm(
    const u16* __restrict__ xb, const u16* __restrict__ Wb,
    const float* __restrict__ bq, const float* __restrict__ bk, const float* __restrict__ bv,
    u16* __restrict__ qt, u16* __restrict__ kt, u16* __restrict__ vt, float scaling) {
  __shared__ __align__(16) u16 As[128 * 64];
  __shared__ __align__(16) u16 Bs[128 * 64];
  const int tid = threadIdx.x, lane = tid & 63, wave = tid >> 6;
  const int wm0 = (wave >> 2) * 64, wn0 = (wave & 3) * 32;
  const int m0 = blockIdx.x * 128, n0 = blockIdx.y * 128, w = blockIdx.z;

  f32x4 acc[4][2];
  #pragma unroll
  for (int mi = 0; mi < 4; ++mi)
    #pragma unroll
    for (int ni = 0; ni < 2; ++ni) acc[mi][ni] = (f32x4){0.f, 0.f, 0.f, 0.f};

  gemm_core_512(xb + (size_t)m0 * 256, 256, Wb + w * 65536 + (size_t)n0 * 256, 256,
                4, As, Bs, tid, lane, wm0, wn0, acc);

  const float* bias = (w == 0) ? bq : (w == 1) ? bk : bv;
  u16* dst = (w == 0) ? qt : (w == 1) ? kt : vt;
  const float sc = (w == 0) ? scaling : 1.0f;

  #pragma unroll
  for (int mi = 0; mi < 4; ++mi)
    #pragma unroll
    for (int ni = 0; ni < 2; ++ni) {
      int f = n0 + wn0 + ni * 16 + (lane & 15);
      int h = f >> 5, d = f & 31;
      float bb = bias[f];
      #pragma unroll
      for (int q = 0; q < 4; ++q) {
        int m = m0 + wm0 + mi * 16 + (lane >> 4) * 4 + q;
        int n = m & 3, i = (m >> 2) & 511, r = m >> 11;
        size_t o = ((size_t)((n * 8 + h) * 512 + i)) * 2048 + r * 32 + d;
        dst[o] = f2bf((acc[mi][ni][q] + bb) * sc);
      }
    }
}

// ---------------- K2a: attention logits GEMM (8-wave variant) --------------
// grid 512, 512 threads, XCD-swizzled. 16 waves/CU (was 8).
__global__ __launch_bounds__(512) void k_attn_mm(
    const u16* __restrict__ qt, const u16* __restrict__ kt, u16* __restrict__ lgt) {
  __shared__ __align__(16) u16 As[128 * 64];
  __shared__ __align__(16) u16 Bs[128 * 64];
  const int tid = threadIdx.x, lane = tid & 63, wave = tid >> 6;
  const int wm0 = (wave >> 2) * 64, wn0 = (wave & 3) * 32;
  const int bid = blockIdx.x;
  const int sb = (bid & 7) * 64 + (bid >> 3);    // 512 % 8 == 0
  const int nh = sb >> 4, tt = sb & 15;
  const int m0 = (tt >> 2) * 128, n0 = (tt & 3) * 128;

  f32x4 acc[4][2];
  #pragma unroll
  for (int mi = 0; mi < 4; ++mi)
    #pragma unroll
    for (int ni = 0; ni < 2; ++ni) acc[mi][ni] = (f32x4){0.f, 0.f, 0.f, 0.f};

  const size_t base = (size_t)nh * 512 * 2048;
  gemm_core_512(qt + base + (size_t)m0 * 2048, 2048, kt + base + (size_t)n0 * 2048, 2048,
                32, As, Bs, tid, lane, wm0, wn0, acc);

  #pragma unroll
  for (int mi = 0; mi < 4; ++mi)
    #pragma unroll
    for (int ni = 0; ni < 2; ++ni) {
      int col = n0 + wn0 + ni * 16 + (lane & 15);
      #pragma unroll
      for (int q = 0; q < 4; ++q) {
        int row = m0 + wm0 + mi * 16 + (lane >> 4) * 4 + q;
        lgt[(size_t)nh * 262144 + (size_t)row * 512 + col] = f2bf(acc[mi][ni][q]);
      }
    }
}

// ---------------- K2b: bias + softmax (barrier-free, per-wave rows) --------
__global__ __launch_bounds__(256) void k_softmax(
    const u16* __restrict__ lgt, const int* __restrict__ dist, const float* __restrict__ rel,
    float* __restrict__ probs, u16* __restrict__ pbf) {
  const int t = threadIdx.x;
  const int lane = t & 63, wv = t >> 6;
  const int b = blockIdx.x;
  const int i = b & 511, n = b >> 9;

  const int* dr = dist + ((size_t)n * 512 + i) * 512 + lane * 8;
  int4 dA = *(const int4*)dr, dB = *(const int4*)(dr + 4);
  int dd[8] = {dA.x, dA.y, dA.z, dA.w, dB.x, dB.y, dB.z, dB.w};
  int u[8];
  #pragma unroll
  for (int j = 0; j < 8; ++j) {
    int v = dd[j] < 0 ? -dd[j] : dd[j];
    int q = (62 * v + 49999) / 50000; if (q > 63) q = 63;
    u[j] = q;
  }

  #pragma unroll
  for (int hh = 0; hh < 2; ++hh) {
    const int h = wv * 2 + hh;
    const int nh = n * 8 + h;
    const u16* lr = lgt + ((size_t)nh * 512 + i) * 512 + lane * 8;
    u16x8 L = *(const u16x8*)lr;
    float vj[8];
    float mx = -1e30f;
    #pragma unroll
    for (int j = 0; j < 8; ++j) {
      vj[j] = bf2f(L[j]) + rel[u[j] * 8 + h];
      mx = fmaxf(mx, vj[j]);
    }
    #pragma unroll
    for (int off = 32; off; off >>= 1) mx = fmaxf(mx, __shfl_xor(mx, off));
    float s = 0.f;
    #pragma unroll
    for (int j = 0; j < 8; ++j) { vj[j] = __expf(vj[j] - mx); s += vj[j]; }
    #pragma unroll
    for (int off = 32; off; off >>= 1) s += __shfl_xor(s, off);
    float inv = 1.0f / s;
    float4 pa, pb;
    pa.x = vj[0]*inv; pa.y = vj[1]*inv; pa.z = vj[2]*inv; pa.w = vj[3]*inv;
    pb.x = vj[4]*inv; pb.y = vj[5]*inv; pb.z = vj[6]*inv; pb.w = vj[7]*inv;
    size_t po = ((size_t)(h * 4 + n) * 512 + i) * 512 + lane * 8;
    *(float4*)(probs + po) = pa;
    *(float4*)(probs + po + 4) = pb;
    u16x8 pc;
    pc[0]=f2bf(pa.x); pc[1]=f2bf(pa.y); pc[2]=f2bf(pa.z); pc[3]=f2bf(pa.w);
    pc[4]=f2bf(pb.x); pc[5]=f2bf(pb.y); pc[6]=f2bf(pb.z); pc[7]=f2bf(pb.w);
    size_t pq = ((size_t)nh * 512 + i) * 512 + lane * 8;
    *(u16x8*)(pbf + pq) = pc;
  }
}

// ---------------- V transpose: vt [nh][i][c] -> vtt [nh][c][i] -------------
__global__ __launch_bounds__(256) void k_vtrans(const u16* __restrict__ vt, u16* __restrict__ vtt) {
  __shared__ u16 ts[64][72];
  const int b = blockIdx.x;             // nh*256 + it*32 + ct
  const int ct_ = b & 31, it = (b >> 5) & 7, nh = b >> 8;
  const int i0 = it * 64, c0 = ct_ * 64;
  const int t = threadIdx.x;
  #pragma unroll
  for (int rep = 0; rep < 2; ++rep) {
    int c = t + rep * 256;
    int r = c >> 3, q = c & 7;
    u16x8 v = *(const u16x8*)(vt + ((size_t)nh * 512 + i0 + r) * 2048 + c0 + q * 8);
    #pragma unroll
    for (int j = 0; j < 8; ++j) ts[r][q * 8 + j] = v[j];
  }
  __syncthreads();
  #pragma unroll
  for (int rep = 0; rep < 2; ++rep) {
    int c = t + rep * 256;
    int rr = c >> 3, q = c & 7;
    u16x8 o;
    #pragma unroll
    for (int j = 0; j < 8; ++j) o[j] = ts[q * 8 + j][rr];
    *(u16x8*)(vtt + ((size_t)nh * 2048 + c0 + rr) * 512 + i0 + q * 8) = o;
  }
}

// ---------------- K3: context GEMM (LDS-transpose epilogue, pad 130) -------
__global__ __launch_bounds__(256) void k_ctx_mm(
    const u16* __restrict__ vtt, const u16* __restrict__ pbf, u16* __restrict__ ct) {
  __shared__ __align__(16) u16 lds[16640];      // staging 16384 U ts 128*130
  u16* As = lds;
  u16* Bs = lds + 8192;
  u16* ts = lds;
  const int tid = threadIdx.x, lane = tid & 63, wave = tid >> 6;
  const int wm0 = (wave >> 1) * 64, wn0 = (wave & 1) * 64;
  const int bid = blockIdx.x;
  const int sb = (bid & 7) * 256 + (bid >> 3);   // 2048 % 8 == 0
  const int nh = sb >> 6, tt = sb & 63;
  const int m0 = (tt >> 2) * 128, n0 = (tt & 3) * 128;
  const int n = nh >> 3, h = nh & 7;

  f32x4 acc[4][4];
  #pragma unroll
  for (int mi = 0; mi < 4; ++mi)
    #pragma unroll
    for (int ni = 0; ni < 4; ++ni) acc[mi][ni] = (f32x4){0.f, 0.f, 0.f, 0.f};

  gemm_core(vtt + (size_t)nh * 1048576 + (size_t)m0 * 512, 512,
            pbf + (size_t)nh * 262144 + (size_t)n0 * 512, 512,
            8, As, Bs, tid, lane, wm0, wn0, acc);

  // ts[i_local][c_local], pad 130
  #pragma unroll
  for (int mi = 0; mi < 4; ++mi)
    #pragma unroll
    for (int ni = 0; ni < 4; ++ni) {
      int i_l = wn0 + ni * 16 + (lane & 15);
      #pragma unroll
      for (int q = 0; q < 4; ++q) {
        int c_l = wm0 + mi * 16 + (lane >> 4) * 4 + q;
        ts[i_l * 130 + c_l] = f2bf(acc[mi][ni][q]);
      }
    }
  __syncthreads();
  #pragma unroll
  for (int cc = 0; cc < 2; ++cc) {
    int ch = tid + cc * 256;
    int i_l = ch & 127, r_l = ch >> 7;
    const u16* src = ts + i_l * 130 + r_l * 32;
    int rr = (m0 >> 5) + r_l;
    size_t o = ((size_t)((rr * 512 + n0 + i_l) * 4 + n)) * 256 + h * 32;
    #pragma unroll
    for (int j = 0; j < 4; ++j)
      *(u16x8*)(ct + o + j * 8) = *(const u16x8*)(src + j * 8);
  }
}

// ---------------- K4: output projection GEMM (round-5 proven form) ---------
__global__ __launch_bounds__(256) void k_oproj_mm(
    const u16* __restrict__ ct, const u16* __restrict__ Wob,
    const float* __restrict__ bo, float* __restrict__ out) {
  __shared__ __align__(16) u16 As[128 * 64];
  __shared__ __align__(16) u16 Bs[128 * 64];
  const int tid = threadIdx.x, lane = tid & 63, wave = tid >> 6;
  const int wm0 = (wave >> 1) * 64, wn0 = (wave & 1) * 64;
  const int bid = blockIdx.x;
  const int sb = (bid & 7) * 256 + (bid >> 3);
  const int m0 = (sb >> 1) * 128, n0 = (sb & 1) * 128;

  f32x4 acc[4][4];
  #pragma unroll
  for (int mi = 0; mi < 4; ++mi)
    #pragma unroll
    for (int ni = 0; ni < 4; ++ni) acc[mi][ni] = (f32x4){0.f, 0.f, 0.f, 0.f};

  gemm_core(ct + (size_t)m0 * 256, 256, Wob + (size_t)n0 * 256, 256,
            4, As, Bs, tid, lane, wm0, wn0, acc);

  #pragma unroll
  for (int mi = 0; mi < 4; ++mi)
    #pragma unroll
    for (int ni = 0; ni < 4; ++ni) {
      int col = n0 + wn0 + ni * 16 + (lane & 15);
      float bb = bo[col];
      #pragma unroll
      for (int q = 0; q < 4; ++q) {
        int row = m0 + wm0 + mi * 16 + (lane >> 4) * 4 + q;
        out[(size_t)row * 256 + col] = acc[mi][ni][q] + bb;
      }
    }
}

extern "C" void kernel_launch(void* const* d_in, const int* in_sizes, int n_in,
                              void* d_out, int out_size, void* d_ws, size_t ws_size,
                              hipStream_t stream) {
  const float* x  = (const float*)d_in[0];
  const int* dist = (const int*)d_in[1];
  const float* Wq = (const float*)d_in[2];
  const float* bq = (const float*)d_in[3];
  const float* Wk = (const float*)d_in[4];
  const float* bk = (const float*)d_in[5];
  const float* Wv = (const float*)d_in[6];
  const float* bv = (const float*)d_in[7];
  const float* Wo = (const float*)d_in[8];
  const float* bo = (const float*)d_in[9];
  const float* rel = (const float*)d_in[10];
  float* out = (float*)d_out;
  float* probs = out + (size_t)SL;        // second output region (H,N,I,J) f32

  u16* ws = (u16*)d_ws;
  // slots: 0: xb -> lgt -> ct ; 1: qt -> pbf ; 2: kt -> vtt ; 3: vt
  u16* xb  = ws;
  u16* qt  = ws + (size_t)SL;
  u16* kt  = ws + (size_t)2 * SL;
  u16* vt  = ws + (size_t)3 * SL;
  u16* lgt = xb;
  u16* pbf = qt;
  u16* vtt = kt;
  u16* ctb = xb;
  u16* Wb  = ws + (size_t)4 * SL;         // 4 x 65536 bf16 weights

  const float scaling = 0.022097086912079608f;   // 32^-0.5 / sqrt(64)

  k_castx  <<<16384, 256, 0, stream>>>(x, xb);
  k_castw  <<<128, 256, 0, stream>>>(Wq, Wk, Wv, Wo, Wb);
  k_proj_mm<<<dim3(1024, 2, 3), 512, 0, stream>>>(xb, Wb, bq, bk, bv, qt, kt, vt, scaling);
  k_attn_mm<<<512, 512, 0, stream>>>(qt, kt, lgt);
  k_softmax<<<2048, 256, 0, stream>>>(lgt, dist, rel, probs, pbf);
  k_vtrans <<<8192, 256, 0, stream>>>(vt, vtt);
  k_ctx_mm <<<2048, 256, 0, stream>>>(vtt, pbf, ctb);
  k_oproj_mm<<<2048, 256, 0, stream>>>(ctb, Wb + 196608, bo, out);
}

// Round 12
// 330.288 us; speedup vs baseline: 1.1562x; 1.0857x over previous
//
#include <hip/hip_runtime.h>

typedef unsigned short u16;
typedef unsigned int u32;
typedef float f32x4 __attribute__((ext_vector_type(4)));
typedef short bf16x8 __attribute__((ext_vector_type(8)));
typedef unsigned short u16x8 __attribute__((ext_vector_type(8)));

#define SL 33554432u   // one 67MB slot, in u16 elements

__device__ __forceinline__ float bf2f(u16 u) {
  u32 v = ((u32)u) << 16;
  return __builtin_bit_cast(float, v);
}
__device__ __forceinline__ u16 f2bf(float f) {
  u32 i = __builtin_bit_cast(u32, f);
  i += 0x7fffu + ((i >> 16) & 1u);
  return (u16)(i >> 16);
}

#define GLDS16(g, l) __builtin_amdgcn_global_load_lds( \
    (const __attribute__((address_space(1))) void*)(g), \
    (__attribute__((address_space(3))) void*)(l), 16, 0, 0)

// ==== 256-thread (4-wave) GEMM core — used by ctx/oproj (proven) ===========
__device__ __forceinline__ void stage128(const u16* gbase, int ldk, u16* lds, int tid) {
  #pragma unroll
  for (int rep = 0; rep < 4; ++rep) {
    int c = tid + rep * 256;            // chunk 0..1023
    int row = c >> 3, slot = c & 7;
    const u16* g = gbase + (size_t)row * ldk + ((slot ^ (row & 7)) << 3);
    GLDS16(g, lds + c * 8);
  }
}

__device__ __forceinline__ void mfma128(const u16* As, const u16* Bs, int lane,
                                        int wm0, int wn0, f32x4 acc[4][4]) {
  #pragma unroll
  for (int kk = 0; kk < 2; ++kk) {
    bf16x8 a[4], b[4];
    #pragma unroll
    for (int mi = 0; mi < 4; ++mi) {
      int r = wm0 + mi * 16 + (lane & 15);
      int c16 = (kk * 4 + (lane >> 4)) ^ (r & 7);
      a[mi] = *(const bf16x8*)(As + r * 64 + c16 * 8);
    }
    #pragma unroll
    for (int ni = 0; ni < 4; ++ni) {
      int r = wn0 + ni * 16 + (lane & 15);
      int c16 = (kk * 4 + (lane >> 4)) ^ (r & 7);
      b[ni] = *(const bf16x8*)(Bs + r * 64 + c16 * 8);
    }
    #pragma unroll
    for (int mi = 0; mi < 4; ++mi)
      #pragma unroll
      for (int ni = 0; ni < 4; ++ni)
        acc[mi][ni] = __builtin_amdgcn_mfma_f32_16x16x32_bf16(a[mi], b[ni], acc[mi][ni], 0, 0, 0);
  }
}

__device__ __forceinline__ void gemm_core(const u16* A, int ldkA, const u16* B, int ldkB,
                                          int NT, u16* As, u16* Bs,
                                          int tid, int lane, int wm0, int wn0,
                                          f32x4 acc[4][4]) {
  for (int t = 0; t < NT; ++t) {
    stage128(A + t * 64, ldkA, As, tid);
    stage128(B + t * 64, ldkB, Bs, tid);
    __syncthreads();
    mfma128(As, Bs, lane, wm0, wn0, acc);
    __syncthreads();
  }
}

// ==== 512-thread (8-wave) helpers ==========================================
__device__ __forceinline__ void stage128_512(const u16* gbase, int ldk, u16* lds, int tid) {
  #pragma unroll
  for (int rep = 0; rep < 2; ++rep) {
    int c = tid + rep * 512;            // chunk 0..1023
    int row = c >> 3, slot = c & 7;
    const u16* g = gbase + (size_t)row * ldk + ((slot ^ (row & 7)) << 3);
    GLDS16(g, lds + c * 8);
  }
}

__device__ __forceinline__ void mfma128_8w(const u16* As, const u16* Bs, int lane,
                                           int wm0, int wn0, f32x4 acc[4][2]) {
  #pragma unroll
  for (int kk = 0; kk < 2; ++kk) {
    bf16x8 a[4], b[2];
    #pragma unroll
    for (int mi = 0; mi < 4; ++mi) {
      int r = wm0 + mi * 16 + (lane & 15);
      int c16 = (kk * 4 + (lane >> 4)) ^ (r & 7);
      a[mi] = *(const bf16x8*)(As + r * 64 + c16 * 8);
    }
    #pragma unroll
    for (int ni = 0; ni < 2; ++ni) {
      int r = wn0 + ni * 16 + (lane & 15);
      int c16 = (kk * 4 + (lane >> 4)) ^ (r & 7);
      b[ni] = *(const bf16x8*)(Bs + r * 64 + c16 * 8);
    }
    #pragma unroll
    for (int mi = 0; mi < 4; ++mi)
      #pragma unroll
      for (int ni = 0; ni < 2; ++ni)
        acc[mi][ni] = __builtin_amdgcn_mfma_f32_16x16x32_bf16(a[mi], b[ni], acc[mi][ni], 0, 0, 0);
  }
}

// ---------------- casts ----------------------------------------------------
__global__ __launch_bounds__(256) void k_castx(const float* __restrict__ src,
                                               u16* __restrict__ dst) {
  int idx = blockIdx.x * 256 + threadIdx.x;     // 4194304 chunks of 8
  const float4* s = (const float4*)src;
  float4 a = s[(size_t)idx * 2], b = s[(size_t)idx * 2 + 1];
  u16x8 o;
  o[0] = f2bf(a.x); o[1] = f2bf(a.y); o[2] = f2bf(a.z); o[3] = f2bf(a.w);
  o[4] = f2bf(b.x); o[5] = f2bf(b.y); o[6] = f2bf(b.z); o[7] = f2bf(b.w);
  *(u16x8*)(dst + (size_t)idx * 8) = o;
}

__global__ __launch_bounds__(256) void k_castw(
    const float* __restrict__ Wq, const float* __restrict__ Wk,
    const float* __restrict__ Wv, const float* __restrict__ Wo,
    u16* __restrict__ Wb) {
  int idx = blockIdx.x * 256 + threadIdx.x;     // 32768 chunks of 8
  int w = idx >> 13, off = idx & 8191;
  const float* src = (w == 0) ? Wq : (w == 1) ? Wk : (w == 2) ? Wv : Wo;
  const float4* s = (const float4*)(src + (size_t)off * 8);
  float4 a = s[0], b = s[1];
  u16x8 o;
  o[0] = f2bf(a.x); o[1] = f2bf(a.y); o[2] = f2bf(a.z); o[3] = f2bf(a.w);
  o[4] = f2bf(b.x); o[5] = f2bf(b.y); o[6] = f2bf(b.z); o[7] = f2bf(b.w);
  *(u16x8*)(Wb + (size_t)w * 65536 + (size_t)off * 8) = o;
}

// ---------------- K1: q/k/v projection GEMM (3-w fused, n-quarter) ---------
// grid 4096 = 1024 m-tiles x 4 n-quarters, 512 threads, XCD-chunked so the
// 4 quarters of an m-tile co-run on one XCD (A-panel read ONCE from HBM).
// Per K-tile: stage A (16KB) + 3x B[64x64] (12KB), 24 MFMA/wave per barrier.
// LDS 40KB -> 4 blocks/CU = 32 waves/CU.
__global__ __launch_bounds__(512) void k_proj_mm(
    const u16* __restrict__ xb, const u16* __restrict__ Wb,
    const float* __restrict__ bq, const float* __restrict__ bk, const float* __restrict__ bv,
    u16* __restrict__ qt, u16* __restrict__ kt, u16* __restrict__ vt, float scaling) {
  __shared__ __align__(16) u16 As[8192];        // [128][64]
  __shared__ __align__(16) u16 Bs[12288];       // 3 x [64][64]
  const int tid = threadIdx.x, lane = tid & 63, wave = tid >> 6;
  const int wm0 = (wave >> 2) * 64, wn0 = (wave & 3) * 16;
  const int bid = blockIdx.x;
  const int sb = (bid & 7) * 512 + (bid >> 3);   // bijective: 4096 % 8 == 0
  const int mt = sb >> 2, nq = sb & 3;
  const int m0 = mt * 128, n0 = nq * 64;

  f32x4 acc[3][4];   // [w][mi], single ni
  #pragma unroll
  for (int w = 0; w < 3; ++w)
    #pragma unroll
    for (int mi = 0; mi < 4; ++mi) acc[w][mi] = (f32x4){0.f, 0.f, 0.f, 0.f};

  for (int t = 0; t < 4; ++t) {
    // stage A: 1024 chunks of 8
    #pragma unroll
    for (int rep = 0; rep < 2; ++rep) {
      int c = tid + rep * 512;
      int row = c >> 3, slot = c & 7;
      GLDS16(xb + (size_t)(m0 + row) * 256 + t * 64 + ((slot ^ (row & 7)) << 3),
             As + c * 8);
    }
    // stage 3 B-tiles: 1536 chunks of 8
    #pragma unroll
    for (int rep = 0; rep < 3; ++rep) {
      int cc = tid + rep * 512;
      int w = cc >> 9, idx = cc & 511;
      int row = idx >> 3, slot = idx & 7;
      GLDS16(Wb + w * 65536 + (size_t)(n0 + row) * 256 + t * 64 + ((slot ^ (row & 7)) << 3),
             Bs + w * 4096 + idx * 8);
    }
    __syncthreads();

    #pragma unroll
    for (int kk = 0; kk < 2; ++kk) {
      bf16x8 a[4];
      #pragma unroll
      for (int mi = 0; mi < 4; ++mi) {
        int r = wm0 + mi * 16 + (lane & 15);
        int c16 = (kk * 4 + (lane >> 4)) ^ (r & 7);
        a[mi] = *(const bf16x8*)(As + r * 64 + c16 * 8);
      }
      int rb = wn0 + (lane & 15);
      int c16b = (kk * 4 + (lane >> 4)) ^ (rb & 7);
      #pragma unroll
      for (int w = 0; w < 3; ++w) {
        bf16x8 b = *(const bf16x8*)(Bs + w * 4096 + rb * 64 + c16b * 8);
        #pragma unroll
        for (int mi = 0; mi < 4; ++mi)
          acc[w][mi] = __builtin_amdgcn_mfma_f32_16x16x32_bf16(a[mi], b, acc[w][mi], 0, 0, 0);
      }
    }
    __syncthreads();
  }

  #pragma unroll
  for (int w = 0; w < 3; ++w) {
    const float* bias = (w == 0) ? bq : (w == 1) ? bk : bv;
    u16* dst = (w == 0) ? qt : (w == 1) ? kt : vt;
    const float sc = (w == 0) ? scaling : 1.0f;
    int f = n0 + wn0 + (lane & 15);
    int h = f >> 5, d = f & 31;
    float bb = bias[f];
    #pragma unroll
    for (int mi = 0; mi < 4; ++mi) {
      #pragma unroll
      for (int q = 0; q < 4; ++q) {
        int m = m0 + wm0 + mi * 16 + (lane >> 4) * 4 + q;
        int n = m & 3, i = (m >> 2) & 511, r = m >> 11;
        size_t o = ((size_t)((n * 8 + h) * 512 + i)) * 2048 + r * 32 + d;
        dst[o] = f2bf((acc[w][mi][q] + bb) * sc);
      }
    }
  }
}

// ---------------- K2a: attention logits GEMM (8-wave, double-buffered) -----
// grid 512, 512 threads, XCD-swizzled. Stage tile t+1 BEFORE computing tile
// t: loads fly under MFMA; single __syncthreads/iter both drains the
// prefetch and releases buf[t]. LDS 64KB -> 2 blocks/CU.
__global__ __launch_bounds__(512) void k_attn_mm(
    const u16* __restrict__ qt, const u16* __restrict__ kt, u16* __restrict__ lgt) {
  __shared__ __align__(16) u16 As[2][8192];
  __shared__ __align__(16) u16 Bs[2][8192];
  const int tid = threadIdx.x, lane = tid & 63, wave = tid >> 6;
  const int wm0 = (wave >> 2) * 64, wn0 = (wave & 3) * 32;
  const int bid = blockIdx.x;
  const int sb = (bid & 7) * 64 + (bid >> 3);    // 512 % 8 == 0
  const int nh = sb >> 4, tt = sb & 15;
  const int m0 = (tt >> 2) * 128, n0 = (tt & 3) * 128;

  f32x4 acc[4][2];
  #pragma unroll
  for (int mi = 0; mi < 4; ++mi)
    #pragma unroll
    for (int ni = 0; ni < 2; ++ni) acc[mi][ni] = (f32x4){0.f, 0.f, 0.f, 0.f};

  const size_t base = (size_t)nh * 512 * 2048;
  const u16* A = qt + base + (size_t)m0 * 2048;
  const u16* B = kt + base + (size_t)n0 * 2048;

  stage128_512(A, 2048, As[0], tid);
  stage128_512(B, 2048, Bs[0], tid);
  __syncthreads();
  for (int t = 0; t < 32; ++t) {
    int cur = t & 1;
    if (t + 1 < 32) {
      stage128_512(A + (t + 1) * 64, 2048, As[cur ^ 1], tid);
      stage128_512(B + (t + 1) * 64, 2048, Bs[cur ^ 1], tid);
    }
    mfma128_8w(As[cur], Bs[cur], lane, wm0, wn0, acc);
    __syncthreads();   // drains t+1 loads; releases buf[cur] for t+2 staging
  }

  #pragma unroll
  for (int mi = 0; mi < 4; ++mi)
    #pragma unroll
    for (int ni = 0; ni < 2; ++ni) {
      int col = n0 + wn0 + ni * 16 + (lane & 15);
      #pragma unroll
      for (int q = 0; q < 4; ++q) {
        int row = m0 + wm0 + mi * 16 + (lane >> 4) * 4 + q;
        lgt[(size_t)nh * 262144 + (size_t)row * 512 + col] = f2bf(acc[mi][ni][q]);
      }
    }
}

// ---------------- K2b: bias + softmax (barrier-free, per-wave rows) --------
__global__ __launch_bounds__(256) void k_softmax(
    const u16* __restrict__ lgt, const int* __restrict__ dist, const float* __restrict__ rel,
    float* __restrict__ probs, u16* __restrict__ pbf) {
  const int t = threadIdx.x;
  const int lane = t & 63, wv = t >> 6;
  const int b = blockIdx.x;
  const int i = b & 511, n = b >> 9;

  const int* dr = dist + ((size_t)n * 512 + i) * 512 + lane * 8;
  int4 dA = *(const int4*)dr, dB = *(const int4*)(dr + 4);
  int dd[8] = {dA.x, dA.y, dA.z, dA.w, dB.x, dB.y, dB.z, dB.w};
  int u[8];
  #pragma unroll
  for (int j = 0; j < 8; ++j) {
    int v = dd[j] < 0 ? -dd[j] : dd[j];
    int q = (62 * v + 49999) / 50000; if (q > 63) q = 63;
    u[j] = q;
  }

  #pragma unroll
  for (int hh = 0; hh < 2; ++hh) {
    const int h = wv * 2 + hh;
    const int nh = n * 8 + h;
    const u16* lr = lgt + ((size_t)nh * 512 + i) * 512 + lane * 8;
    u16x8 L = *(const u16x8*)lr;
    float vj[8];
    float mx = -1e30f;
    #pragma unroll
    for (int j = 0; j < 8; ++j) {
      vj[j] = bf2f(L[j]) + rel[u[j] * 8 + h];
      mx = fmaxf(mx, vj[j]);
    }
    #pragma unroll
    for (int off = 32; off; off >>= 1) mx = fmaxf(mx, __shfl_xor(mx, off));
    float s = 0.f;
    #pragma unroll
    for (int j = 0; j < 8; ++j) { vj[j] = __expf(vj[j] - mx); s += vj[j]; }
    #pragma unroll
    for (int off = 32; off; off >>= 1) s += __shfl_xor(s, off);
    float inv = 1.0f / s;
    float4 pa, pb;
    pa.x = vj[0]*inv; pa.y = vj[1]*inv; pa.z = vj[2]*inv; pa.w = vj[3]*inv;
    pb.x = vj[4]*inv; pb.y = vj[5]*inv; pb.z = vj[6]*inv; pb.w = vj[7]*inv;
    size_t po = ((size_t)(h * 4 + n) * 512 + i) * 512 + lane * 8;
    *(float4*)(probs + po) = pa;
    *(float4*)(probs + po + 4) = pb;
    u16x8 pc;
    pc[0]=f2bf(pa.x); pc[1]=f2bf(pa.y); pc[2]=f2bf(pa.z); pc[3]=f2bf(pa.w);
    pc[4]=f2bf(pb.x); pc[5]=f2bf(pb.y); pc[6]=f2bf(pb.z); pc[7]=f2bf(pb.w);
    size_t pq = ((size_t)nh * 512 + i) * 512 + lane * 8;
    *(u16x8*)(pbf + pq) = pc;
  }
}

// ---------------- V transpose: vt [nh][i][c] -> vtt [nh][c][i] -------------
__global__ __launch_bounds__(256) void k_vtrans(const u16* __restrict__ vt, u16* __restrict__ vtt) {
  __shared__ u16 ts[64][72];
  const int b = blockIdx.x;             // nh*256 + it*32 + ct
  const int ct_ = b & 31, it = (b >> 5) & 7, nh = b >> 8;
  const int i0 = it * 64, c0 = ct_ * 64;
  const int t = threadIdx.x;
  #pragma unroll
  for (int rep = 0; rep < 2; ++rep) {
    int c = t + rep * 256;
    int r = c >> 3, q = c & 7;
    u16x8 v = *(const u16x8*)(vt + ((size_t)nh * 512 + i0 + r) * 2048 + c0 + q * 8);
    #pragma unroll
    for (int j = 0; j < 8; ++j) ts[r][q * 8 + j] = v[j];
  }
  __syncthreads();
  #pragma unroll
  for (int rep = 0; rep < 2; ++rep) {
    int c = t + rep * 256;
    int rr = c >> 3, q = c & 7;
    u16x8 o;
    #pragma unroll
    for (int j = 0; j < 8; ++j) o[j] = ts[q * 8 + j][rr];
    *(u16x8*)(vtt + ((size_t)nh * 2048 + c0 + rr) * 512 + i0 + q * 8) = o;
  }
}

// ---------------- K3: context GEMM (LDS-transpose epilogue, pad 130) -------
__global__ __launch_bounds__(256) void k_ctx_mm(
    const u16* __restrict__ vtt, const u16* __restrict__ pbf, u16* __restrict__ ct) {
  __shared__ __align__(16) u16 lds[16640];      // staging 16384 U ts 128*130
  u16* As = lds;
  u16* Bs = lds + 8192;
  u16* ts = lds;
  const int tid = threadIdx.x, lane = tid & 63, wave = tid >> 6;
  const int wm0 = (wave >> 1) * 64, wn0 = (wave & 1) * 64;
  const int bid = blockIdx.x;
  const int sb = (bid & 7) * 256 + (bid >> 3);   // 2048 % 8 == 0
  const int nh = sb >> 6, tt = sb & 63;
  const int m0 = (tt >> 2) * 128, n0 = (tt & 3) * 128;
  const int n = nh >> 3, h = nh & 7;

  f32x4 acc[4][4];
  #pragma unroll
  for (int mi = 0; mi < 4; ++mi)
    #pragma unroll
    for (int ni = 0; ni < 4; ++ni) acc[mi][ni] = (f32x4){0.f, 0.f, 0.f, 0.f};

  gemm_core(vtt + (size_t)nh * 1048576 + (size_t)m0 * 512, 512,
            pbf + (size_t)nh * 262144 + (size_t)n0 * 512, 512,
            8, As, Bs, tid, lane, wm0, wn0, acc);

  // ts[i_local][c_local], pad 130
  #pragma unroll
  for (int mi = 0; mi < 4; ++mi)
    #pragma unroll
    for (int ni = 0; ni < 4; ++ni) {
      int i_l = wn0 + ni * 16 + (lane & 15);
      #pragma unroll
      for (int q = 0; q < 4; ++q) {
        int c_l = wm0 + mi * 16 + (lane >> 4) * 4 + q;
        ts[i_l * 130 + c_l] = f2bf(acc[mi][ni][q]);
      }
    }
  __syncthreads();
  #pragma unroll
  for (int cc = 0; cc < 2; ++cc) {
    int ch = tid + cc * 256;
    int i_l = ch & 127, r_l = ch >> 7;
    const u16* src = ts + i_l * 130 + r_l * 32;
    int rr = (m0 >> 5) + r_l;
    size_t o = ((size_t)((rr * 512 + n0 + i_l) * 4 + n)) * 256 + h * 32;
    #pragma unroll
    for (int j = 0; j < 4; ++j)
      *(u16x8*)(ct + o + j * 8) = *(const u16x8*)(src + j * 8);
  }
}

// ---------------- K4: output projection GEMM (round-5 proven form) ---------
__global__ __launch_bounds__(256) void k_oproj_mm(
    const u16* __restrict__ ct, const u16* __restrict__ Wob,
    const float* __restrict__ bo, float* __restrict__ out) {
  __shared__ __align__(16) u16 As[128 * 64];
  __shared__ __align__(16) u16 Bs[128 * 64];
  const int tid = threadIdx.x, lane = tid & 63, wave = tid >> 6;
  const int wm0 = (wave >> 1) * 64, wn0 = (wave & 1) * 64;
  const int bid = blockIdx.x;
  const int sb = (bid & 7) * 256 + (bid >> 3);
  const int m0 = (sb >> 1) * 128, n0 = (sb & 1) * 128;

  f32x4 acc[4][4];
  #pragma unroll
  for (int mi = 0; mi < 4; ++mi)
    #pragma unroll
    for (int ni = 0; ni < 4; ++ni) acc[mi][ni] = (f32x4){0.f, 0.f, 0.f, 0.f};

  gemm_core(ct + (size_t)m0 * 256, 256, Wob + (size_t)n0 * 256, 256,
            4, As, Bs, tid, lane, wm0, wn0, acc);

  #pragma unroll
  for (int mi = 0; mi < 4; ++mi)
    #pragma unroll
    for (int ni = 0; ni < 4; ++ni) {
      int col = n0 + wn0 + ni * 16 + (lane & 15);
      float bb = bo[col];
      #pragma unroll
      for (int q = 0; q < 4; ++q) {
        int row = m0 + wm0 + mi * 16 + (lane >> 4) * 4 + q;
        out[(size_t)row * 256 + col] = acc[mi][ni][q] + bb;
      }
    }
}

extern "C" void kernel_launch(void* const* d_in, const int* in_sizes, int n_in,
                              void* d_out, int out_size, void* d_ws, size_t ws_size,
                              hipStream_t stream) {
  const float* x  = (const float*)d_in[0];
  const int* dist = (const int*)d_in[1];
  const float* Wq = (const float*)d_in[2];
  const float* bq = (const float*)d_in[3];
  const float* Wk = (const float*)d_in[4];
  const float* bk = (const float*)d_in[5];
  const float* Wv = (const float*)d_in[6];
  const float* bv = (const float*)d_in[7];
  const float* Wo = (const float*)d_in[8];
  const float* bo = (const float*)d_in[9];
  const float* rel = (const float*)d_in[10];
  float* out = (float*)d_out;
  float* probs = out + (size_t)SL;        // second output region (H,N,I,J) f32

  u16* ws = (u16*)d_ws;
  // slots: 0: xb -> lgt -> ct ; 1: qt -> pbf ; 2: kt -> vtt ; 3: vt
  u16* xb  = ws;
  u16* qt  = ws + (size_t)SL;
  u16* kt  = ws + (size_t)2 * SL;
  u16* vt  = ws + (size_t)3 * SL;
  u16* lgt = xb;
  u16* pbf = qt;
  u16* vtt = kt;
  u16* ctb = xb;
  u16* Wb  = ws + (size_t)4 * SL;         // 4 x 65536 bf16 weights

  const float scaling = 0.022097086912079608f;   // 32^-0.5 / sqrt(64)

  k_castx  <<<16384, 256, 0, stream>>>(x, xb);
  k_castw  <<<128, 256, 0, stream>>>(Wq, Wk, Wv, Wo, Wb);
  k_proj_mm<<<4096, 512, 0, stream>>>(xb, Wb, bq, bk, bv, qt, kt, vt, scaling);
  k_attn_mm<<<512, 512, 0, stream>>>(qt, kt, lgt);
  k_softmax<<<2048, 256, 0, stream>>>(lgt, dist, rel, probs, pbf);
  k_vtrans <<<8192, 256, 0, stream>>>(vt, vtt);
  k_ctx_mm <<<2048, 256, 0, stream>>>(vtt, pbf, ctb);
  k_oproj_mm<<<2048, 256, 0, stream>>>(ctb, Wb + 196608, bo, out);
}